// Round 10
// baseline (568.885 us; speedup 1.0000x reference)
//
#include <hip/hip_runtime.h>
#include <math.h>

typedef unsigned short u16;
typedef __attribute__((ext_vector_type(4))) float f32x4;
typedef __attribute__((ext_vector_type(8))) __bf16 bf16x8;
typedef __attribute__((ext_vector_type(8))) short s16x8;

#define AS1 __attribute__((address_space(1)))
#define AS3 __attribute__((address_space(3)))

__device__ __forceinline__ u16 cvt(float f) {
  __bf16 h = (__bf16)f;
  return *(u16*)&h;
}

__device__ __forceinline__ float fexp2(float x) {
  float r;
  asm volatile("v_exp_f32 %0, %1" : "=v"(r) : "v"(x));
  return r;
}

__device__ __forceinline__ void load_lds16(const void* g, void* l) {
  __builtin_amdgcn_global_load_lds((AS1 void*)g, (AS3 void*)l, 16, 0, 0);
}

__device__ __forceinline__ f32x4 mfma16(bf16x8 a, bf16x8 b, f32x4 c) {
  return __builtin_amdgcn_mfma_f32_16x16x32_bf16(a, b, c, 0, 0, 0);
}

// ---------------- merged weight transpose fp32 -> bf16, W[K][N] -> WT[N][K] ----------------
struct WT8 {
  const float* src[8];
  u16* dst[8];
  int K[8];
  int N[8];
  int cnt[8];  // (N/32)*(K/32)
};

__global__ void wtrans_all(WT8 a) {
  __shared__ float t[32][33];
  int rem = blockIdx.x, i = 0;
  while (rem >= a.cnt[i]) { rem -= a.cnt[i]; ++i; }
  const int nb = a.N[i] >> 5;
  const int n0 = (rem % nb) * 32, k0 = (rem / nb) * 32;
  const float* W = a.src[i];
  u16* WT = a.dst[i];
  const int K = a.K[i], N = a.N[i];
  for (int r = threadIdx.y; r < 32; r += 8)
    t[r][threadIdx.x] = W[(size_t)(k0 + r) * N + n0 + threadIdx.x];
  __syncthreads();
  for (int r = threadIdx.y; r < 32; r += 8)
    WT[(size_t)(n0 + r) * K + k0 + threadIdx.x] = cvt(t[threadIdx.x][r]);
}

// ---------------- LayerNorm fp32 -> bf16 (row = 768) ----------------
__global__ __launch_bounds__(256)
void ln_bf16(const float* __restrict__ in, const float* __restrict__ g,
             const float* __restrict__ be, u16* __restrict__ out) {
  const int row = blockIdx.x, tid = threadIdx.x;
  const float* x = in + (size_t)row * 768;
  float v0 = x[tid], v1 = x[tid + 256], v2 = x[tid + 512];
  float s = v0 + v1 + v2;
  for (int m = 1; m < 64; m <<= 1) s += __shfl_xor(s, m);
  __shared__ float red[8];
  const int w = tid >> 6, lane = tid & 63;
  if (lane == 0) red[w] = s;
  __syncthreads();
  s = red[0] + red[1] + red[2] + red[3];
  const float mean = s * (1.f / 768.f);
  const float d0 = v0 - mean, d1 = v1 - mean, d2 = v2 - mean;
  float q = d0 * d0 + d1 * d1 + d2 * d2;
  for (int m = 1; m < 64; m <<= 1) q += __shfl_xor(q, m);
  if (lane == 0) red[4 + w] = q;
  __syncthreads();
  q = red[4] + red[5] + red[6] + red[7];
  const float rstd = rsqrtf(q * (1.f / 768.f) + 1e-5f);
  u16* o = out + (size_t)row * 768;
  o[tid]       = cvt(d0 * rstd * g[tid]       + be[tid]);
  o[tid + 256] = cvt(d1 * rstd * g[tid + 256] + be[tid + 256]);
  o[tid + 512] = cvt(d2 * rstd * g[tid + 512] + be[tid + 512]);
}

// ---------------- GEMM: C[M][N] = A[M][K] * BT[N][K]^T ----------------
// Double-buffered LDS staging, one barrier per K-step.
// EPI 0: bf16 out (ldc stride). EPI 1: fp32 out = acc + bias + resid. EPI 2: bf16 gelu(acc+bias).
template <int EPI>
__global__ __launch_bounds__(256, 3)
void gemm_bt(const u16* __restrict__ A, const u16* __restrict__ BT,
             const float* __restrict__ bias, const float* resid,
             void* outp, int M, int N, int K, int ldc) {
  __shared__ u16 As[2][128 * 32];
  __shared__ u16 Bs[2][128 * 32];
  const int tid = threadIdx.x;
  const int lane = tid & 63, w = tid >> 6;
  const int row0 = blockIdx.y * 128, col0 = blockIdx.x * 128;
  const int wm = (w >> 1) * 64, wn = (w & 1) * 64;
  const int lr = lane & 15, lk = (lane >> 4) * 8;
  const int srow = lane >> 2, scol = (lane & 3) * 8;

  f32x4 acc[4][4] = {};

#define GSTAGE(bi, k0)                                                                    \
  do {                                                                                    \
    _Pragma("unroll") for (int i_ = 0; i_ < 2; ++i_) {                                    \
      const int chunk = w * 2 + i_;                                                       \
      load_lds16(A + (size_t)(row0 + chunk * 16 + srow) * K + (k0) + scol,                \
                 &As[bi][chunk * 512]);                                                   \
      load_lds16(BT + (size_t)(col0 + chunk * 16 + srow) * K + (k0) + scol,               \
                 &Bs[bi][chunk * 512]);                                                   \
    }                                                                                     \
  } while (0)

  GSTAGE(0, 0);
  __syncthreads();
  int cur = 0;

  for (int k0 = 0; k0 < K; k0 += 32) {
    if (k0 + 32 < K) GSTAGE(cur ^ 1, k0 + 32);  // prefetch next K-step
    bf16x8 af[4], bf[4];
#pragma unroll
    for (int mi = 0; mi < 4; ++mi) af[mi] = *(const bf16x8*)&As[cur][(wm + mi * 16 + lr) * 32 + lk];
#pragma unroll
    for (int ni = 0; ni < 4; ++ni) bf[ni] = *(const bf16x8*)&Bs[cur][(wn + ni * 16 + lr) * 32 + lk];
#pragma unroll
    for (int mi = 0; mi < 4; ++mi)
#pragma unroll
      for (int ni = 0; ni < 4; ++ni)
        acc[mi][ni] = mfma16(af[mi], bf[ni], acc[mi][ni]);
    __syncthreads();  // drains prefetch vmcnt + all waves done reading buf[cur]
    cur ^= 1;
  }
#undef GSTAGE

  const int rbase = (lane >> 4) * 4;
#pragma unroll
  for (int mi = 0; mi < 4; ++mi) {
#pragma unroll
    for (int ni = 0; ni < 4; ++ni) {
#pragma unroll
      for (int rr = 0; rr < 4; ++rr) {
        const int r = row0 + wm + mi * 16 + rbase + rr;
        const int c = col0 + wn + ni * 16 + lr;
        float v = acc[mi][ni][rr];
        if (EPI == 0) {
          ((u16*)outp)[(size_t)r * ldc + c] = cvt(v);
        } else if (EPI == 1) {
          ((float*)outp)[(size_t)r * ldc + c] = v + bias[c] + resid[(size_t)r * ldc + c];
        } else {
          v += bias[c];
          v = 0.5f * v * (1.f + erff(v * 0.70710678118654752f));
          ((u16*)outp)[(size_t)r * ldc + c] = cvt(v);
        }
      }
    }
  }
}

// ---------------- Flash attention (QBLK=128: 2 q-groups per wave) ----------------
// qk: [8192][1536] bf16 (q at col h*64, k at col 768+h*64), vt: [768][8192] bf16 (V^T, row h*64+d)
// out: [8192][768] bf16
__global__ __launch_bounds__(256, 2)
void flash_attn(const u16* __restrict__ qk, const u16* __restrict__ vt, u16* __restrict__ out) {
  __shared__ u16 Ks[2][64 * 64];  // K tile [kv][d], chunk-swizzled, double-buffered
  __shared__ u16 Vs[2][64 * 64];  // V^T tile [d][kv], chunk-swizzled, double-buffered
  __shared__ u16 Os[16 * 64];     // ones tile (rowsum-via-MFMA)
  __shared__ u16 P[128 * 72];     // P [qrow][kv], stride 72, per-warp private rows
  const int tid = threadIdx.x, lane = tid & 63, w = tid >> 6;
  const int b = blockIdx.z, h = blockIdx.y, qb = blockIdx.x;
  const u16* qp = qk + (size_t)b * 2048 * 1536 + h * 64;
  const u16* kp = qp + 768;
  const u16* vtp = vt + (size_t)(h * 64) * 8192 + b * 2048;
  const int lr = lane & 15, g = lane >> 4, lk = g * 8;
  const int qrow = qb * 128 + w * 32;

  // ones tile init (bf16 1.0 pairs)
  {
    unsigned* p32 = (unsigned*)Os;
    p32[tid] = 0x3f803f80u;
    p32[tid + 256] = 0x3f803f80u;
  }

  // Q fragments for 2 q-groups, pre-scaled by 0.125 * log2(e) (exp2 domain)
  bf16x8 qf[2][2];
#pragma unroll
  for (int gq = 0; gq < 2; ++gq) {
#pragma unroll
    for (int t = 0; t < 2; ++t) {
      s16x8 qr = *(const s16x8*)&qp[(size_t)(qrow + gq * 16 + lr) * 1536 + t * 32 + lk];
      bf16x8 f;
#pragma unroll
      for (int j = 0; j < 8; ++j) {
        unsigned u = (unsigned)(u16)qr[j] << 16;
        f[j] = (__bf16)(__uint_as_float(u) * 0.18033688f);
      }
      qf[gq][t] = f;
    }
  }

  f32x4 o[2][5] = {};  // [gq][0..3]: output d-tiles; [gq][4]: row-sum (ones column)
  float rowm[2][4];
#pragma unroll
  for (int gq = 0; gq < 2; ++gq)
#pragma unroll
    for (int rr = 0; rr < 4; ++rr) rowm[gq][rr] = -1e30f;

#define STAGE(bi, kv)                                                          \
  do {                                                                         \
    _Pragma("unroll") for (int i_ = 0; i_ < 2; ++i_) {                         \
      const int ch = i_ * 256 + tid;                                           \
      const int r_ = ch >> 3, c_ = ch & 7, cs_ = c_ ^ (r_ & 7);                \
      load_lds16(kp + (size_t)((kv) + r_) * 1536 + cs_ * 8, &Ks[bi][ch * 8]);  \
      load_lds16(vtp + (size_t)r_ * 8192 + (kv) + cs_ * 8, &Vs[bi][ch * 8]);   \
    }                                                                          \
  } while (0)

  STAGE(0, 0);
  __syncthreads();
  int cur = 0;

  for (int kv0 = 0; kv0 < 2048; kv0 += 64) {
    if (kv0 + 64 < 2048) STAGE(cur ^ 1, kv0 + 64);  // prefetch next tile; lands by the barrier

    // QK^T for both q-groups: each K fragment read feeds 2 MFMAs
    f32x4 s[2][4] = {};
#pragma unroll
    for (int t = 0; t < 2; ++t) {
#pragma unroll
      for (int ni = 0; ni < 4; ++ni) {
        const int r = ni * 16 + lr;
        bf16x8 kf = *(const bf16x8*)&Ks[cur][r * 64 + ((4 * t + g) ^ (lr & 7)) * 8];
        s[0][ni] = mfma16(qf[0][t], kf, s[0][ni]);
        s[1][ni] = mfma16(qf[1][t], kf, s[1][ni]);
      }
    }

    // defer-max: shfl-free common path; joint wave-uniform branch for both groups
    float lm[2][4];
#pragma unroll
    for (int gq = 0; gq < 2; ++gq)
#pragma unroll
      for (int rr = 0; rr < 4; ++rr)
        lm[gq][rr] = fmaxf(fmaxf(s[gq][0][rr], s[gq][1][rr]), fmaxf(s[gq][2][rr], s[gq][3][rr]));
    int ok = 1;
#pragma unroll
    for (int gq = 0; gq < 2; ++gq)
#pragma unroll
      for (int rr = 0; rr < 4; ++rr) ok &= (lm[gq][rr] <= rowm[gq][rr] + 8.f);
    if (!__all(ok)) {
#pragma unroll
      for (int gq = 0; gq < 2; ++gq) {
        float alpha[4];
#pragma unroll
        for (int rr = 0; rr < 4; ++rr) {
          float v = lm[gq][rr];
          v = fmaxf(v, __shfl_xor(v, 1));
          v = fmaxf(v, __shfl_xor(v, 2));
          v = fmaxf(v, __shfl_xor(v, 4));
          v = fmaxf(v, __shfl_xor(v, 8));
          const float mn = fmaxf(rowm[gq][rr], v);
          alpha[rr] = fexp2(rowm[gq][rr] - mn);
          rowm[gq][rr] = mn;
        }
#pragma unroll
        for (int di = 0; di < 5; ++di)
#pragma unroll
          for (int rr = 0; rr < 4; ++rr) o[gq][di][rr] *= alpha[rr];
      }
    }

    // P = exp2(S - rowm), bf16, staged to per-warp LDS rows (same-wave write->read)
#pragma unroll
    for (int gq = 0; gq < 2; ++gq) {
      const int prow = w * 32 + gq * 16 + g * 4;
#pragma unroll
      for (int ni = 0; ni < 4; ++ni)
#pragma unroll
        for (int rr = 0; rr < 4; ++rr)
          P[(prow + rr) * 72 + ni * 16 + lr] = cvt(fexp2(s[gq][ni][rr] - rowm[gq][rr]));
    }

    // PV: each V fragment read feeds 2 MFMAs; di=4 row-sum against ones tile
#pragma unroll
    for (int t = 0; t < 2; ++t) {
      bf16x8 pa0 = *(const bf16x8*)&P[(w * 32 + lr) * 72 + t * 32 + lk];
      bf16x8 pa1 = *(const bf16x8*)&P[(w * 32 + 16 + lr) * 72 + t * 32 + lk];
#pragma unroll
      for (int di = 0; di < 4; ++di) {
        bf16x8 vb = *(const bf16x8*)&Vs[cur][(di * 16 + lr) * 64 + ((4 * t + g) ^ (lr & 7)) * 8];
        o[0][di] = mfma16(pa0, vb, o[0][di]);
        o[1][di] = mfma16(pa1, vb, o[1][di]);
      }
      bf16x8 ob = *(const bf16x8*)&Os[lr * 64 + ((4 * t + g) ^ (lr & 7)) * 8];
      o[0][4] = mfma16(pa0, ob, o[0][4]);
      o[1][4] = mfma16(pa1, ob, o[1][4]);
    }

    __syncthreads();  // drains prefetch (vmcnt) + all waves done reading buf[cur]
    cur ^= 1;
  }
#undef STAGE

  const int rbase = g * 4;
#pragma unroll
  for (int gq = 0; gq < 2; ++gq) {
    float inv[4];
#pragma unroll
    for (int rr = 0; rr < 4; ++rr) inv[rr] = 1.0f / o[gq][4][rr];
#pragma unroll
    for (int di = 0; di < 4; ++di) {
#pragma unroll
      for (int rr = 0; rr < 4; ++rr) {
        const int n = qrow + gq * 16 + rbase + rr;
        out[((size_t)b * 2048 + n) * 768 + h * 64 + di * 16 + lr] = cvt(o[gq][di][rr] * inv[rr]);
      }
    }
  }
}

extern "C" void kernel_launch(void* const* d_in, const int* in_sizes, int n_in,
                              void* d_out, int out_size, void* d_ws, size_t ws_size,
                              hipStream_t stream) {
  const float* x     = (const float*)d_in[0];
  const float* y     = (const float*)d_in[1];
  const float* g1    = (const float*)d_in[4];
  const float* be1   = (const float*)d_in[5];
  const float* g2    = (const float*)d_in[6];
  const float* be2   = (const float*)d_in[7];
  const float* g3    = (const float*)d_in[8];
  const float* be3   = (const float*)d_in[9];
  const float* gy    = (const float*)d_in[10];
  const float* bey   = (const float*)d_in[11];
  const float* Wqkv  = (const float*)d_in[12];
  const float* Wo_sa = (const float*)d_in[13];
  const float* bo_sa = (const float*)d_in[14];
  const float* Wq    = (const float*)d_in[15];
  const float* Wk    = (const float*)d_in[16];
  const float* Wv    = (const float*)d_in[17];
  const float* Wo_ca = (const float*)d_in[18];
  const float* bo_ca = (const float*)d_in[19];
  const float* W1    = (const float*)d_in[20];
  const float* b1    = (const float*)d_in[21];
  const float* W2    = (const float*)d_in[22];
  const float* b2    = (const float*)d_in[23];

  // workspace (u16 units), total 94.4 MB
  u16* WqkvT = (u16*)d_ws;                        // [2304][768]
  u16* WoSaT = WqkvT + (size_t)2304 * 768;        // [768][768]
  u16* WqT   = WoSaT + (size_t)768 * 768;
  u16* WkT   = WqT   + (size_t)768 * 768;
  u16* WvT   = WkT   + (size_t)768 * 768;
  u16* WoCaT = WvT   + (size_t)768 * 768;
  u16* W1T   = WoCaT + (size_t)768 * 768;         // [3072][768]
  u16* W2T   = W1T   + (size_t)3072 * 768;        // [768][3072]
  u16* R1    = W2T   + (size_t)768 * 3072;        // [8192][3072]: qk [8192][1536] / mlp hidden
  u16* VT    = R1    + (size_t)8192 * 1536;       // [768][8192] V^T (upper half of R1 region)
  u16* R2    = R1    + (size_t)8192 * 3072;       // [8192][768]
  u16* R3    = R2    + (size_t)8192 * 768;        // [8192][768]
  float* xo  = (float*)d_out;                     // fp32 residual spine x1/x2/out

  WT8 wa;
  {
    const float* s8[8] = {Wqkv, Wo_sa, Wq, Wk, Wv, Wo_ca, W1, W2};
    u16* d8[8] = {WqkvT, WoSaT, WqT, WkT, WvT, WoCaT, W1T, W2T};
    const int K8[8] = {768, 768, 768, 768, 768, 768, 768, 3072};
    const int N8[8] = {2304, 768, 768, 768, 768, 768, 3072, 768};
    for (int i = 0; i < 8; ++i) {
      wa.src[i] = s8[i]; wa.dst[i] = d8[i];
      wa.K[i] = K8[i]; wa.N[i] = N8[i];
      wa.cnt[i] = (N8[i] / 32) * (K8[i] / 32);
    }
  }
  wtrans_all<<<9216, dim3(32, 8), 0, stream>>>(wa);

  // --- self attention ---
  ln_bf16<<<8192, 256, 0, stream>>>(x, g1, be1, R2);
  gemm_bt<0><<<dim3(12, 64), 256, 0, stream>>>(R2, WqkvT, nullptr, nullptr, R1, 8192, 1536, 768, 1536);
  gemm_bt<0><<<dim3(64, 6), 256, 0, stream>>>(WqkvT + (size_t)1536 * 768, R2, nullptr, nullptr, VT, 768, 8192, 768, 8192);
  flash_attn<<<dim3(16, 12, 4), 256, 0, stream>>>(R1, VT, R2);
  gemm_bt<1><<<dim3(6, 64), 256, 0, stream>>>(R2, WoSaT, bo_sa, x, xo, 8192, 768, 768, 768);

  // --- cross attention ---
  ln_bf16<<<8192, 256, 0, stream>>>(y, gy, bey, R3);
  ln_bf16<<<8192, 256, 0, stream>>>(xo, g2, be2, R2);
  gemm_bt<0><<<dim3(6, 64), 256, 0, stream>>>(R2, WqT, nullptr, nullptr, R1, 8192, 768, 768, 1536);
  gemm_bt<0><<<dim3(6, 64), 256, 0, stream>>>(R3, WkT, nullptr, nullptr, R1 + 768, 8192, 768, 768, 1536);
  gemm_bt<0><<<dim3(64, 6), 256, 0, stream>>>(WvT, R3, nullptr, nullptr, VT, 768, 8192, 768, 8192);
  flash_attn<<<dim3(16, 12, 4), 256, 0, stream>>>(R1, VT, R3);
  gemm_bt<1><<<dim3(6, 64), 256, 0, stream>>>(R3, WoCaT, bo_ca, xo, xo, 8192, 768, 768, 768);

  // --- MLP ---
  ln_bf16<<<8192, 256, 0, stream>>>(xo, g3, be3, R2);
  gemm_bt<2><<<dim3(24, 64), 256, 0, stream>>>(R2, W1T, b1, nullptr, R1, 8192, 3072, 768, 3072);
  gemm_bt<1><<<dim3(6, 64), 256, 0, stream>>>(R1, W2T, b2, xo, xo, 8192, 768, 3072, 768);
}

// Round 11
// 534.110 us; speedup vs baseline: 1.0651x; 1.0651x over previous
//
#include <hip/hip_runtime.h>
#include <math.h>

typedef unsigned short u16;
typedef __attribute__((ext_vector_type(4))) float f32x4;
typedef __attribute__((ext_vector_type(8))) __bf16 bf16x8;
typedef __attribute__((ext_vector_type(8))) short s16x8;

#define AS1 __attribute__((address_space(1)))
#define AS3 __attribute__((address_space(3)))

__device__ __forceinline__ u16 cvt(float f) {
  __bf16 h = (__bf16)f;
  return *(u16*)&h;
}

__device__ __forceinline__ float fexp2(float x) {
  float r;
  asm volatile("v_exp_f32 %0, %1" : "=v"(r) : "v"(x));
  return r;
}

__device__ __forceinline__ void load_lds16(const void* g, void* l) {
  __builtin_amdgcn_global_load_lds((AS1 void*)g, (AS3 void*)l, 16, 0, 0);
}

__device__ __forceinline__ f32x4 mfma16(bf16x8 a, bf16x8 b, f32x4 c) {
  return __builtin_amdgcn_mfma_f32_16x16x32_bf16(a, b, c, 0, 0, 0);
}

// ---------------- merged weight transpose fp32 -> bf16, W[K][N] -> WT[N][K] ----------------
struct WT8 {
  const float* src[8];
  u16* dst[8];
  int K[8];
  int N[8];
  int cnt[8];  // (N/32)*(K/32)
};

__global__ void wtrans_all(WT8 a) {
  __shared__ float t[32][33];
  int rem = blockIdx.x, i = 0;
  while (rem >= a.cnt[i]) { rem -= a.cnt[i]; ++i; }
  const int nb = a.N[i] >> 5;
  const int n0 = (rem % nb) * 32, k0 = (rem / nb) * 32;
  const float* W = a.src[i];
  u16* WT = a.dst[i];
  const int K = a.K[i], N = a.N[i];
  for (int r = threadIdx.y; r < 32; r += 8)
    t[r][threadIdx.x] = W[(size_t)(k0 + r) * N + n0 + threadIdx.x];
  __syncthreads();
  for (int r = threadIdx.y; r < 32; r += 8)
    WT[(size_t)(n0 + r) * K + k0 + threadIdx.x] = cvt(t[threadIdx.x][r]);
}

// ---------------- LayerNorm fp32 -> bf16 (row = 768) ----------------
__global__ __launch_bounds__(256)
void ln_bf16(const float* __restrict__ in, const float* __restrict__ g,
             const float* __restrict__ be, u16* __restrict__ out) {
  const int row = blockIdx.x, tid = threadIdx.x;
  const float* x = in + (size_t)row * 768;
  float v0 = x[tid], v1 = x[tid + 256], v2 = x[tid + 512];
  float s = v0 + v1 + v2;
  for (int m = 1; m < 64; m <<= 1) s += __shfl_xor(s, m);
  __shared__ float red[8];
  const int w = tid >> 6, lane = tid & 63;
  if (lane == 0) red[w] = s;
  __syncthreads();
  s = red[0] + red[1] + red[2] + red[3];
  const float mean = s * (1.f / 768.f);
  const float d0 = v0 - mean, d1 = v1 - mean, d2 = v2 - mean;
  float q = d0 * d0 + d1 * d1 + d2 * d2;
  for (int m = 1; m < 64; m <<= 1) q += __shfl_xor(q, m);
  if (lane == 0) red[4 + w] = q;
  __syncthreads();
  q = red[4] + red[5] + red[6] + red[7];
  const float rstd = rsqrtf(q * (1.f / 768.f) + 1e-5f);
  u16* o = out + (size_t)row * 768;
  o[tid]       = cvt(d0 * rstd * g[tid]       + be[tid]);
  o[tid + 256] = cvt(d1 * rstd * g[tid + 256] + be[tid + 256]);
  o[tid + 512] = cvt(d2 * rstd * g[tid + 512] + be[tid + 512]);
}

// ---------------- GEMM: C[M][N] = A[M][K] * BT[N][K]^T ----------------
// BM=128: 4 waves, 64x64 each (big GEMMs). BM=64: 4 waves, 64x32 each (grid-starved GEMMs).
// EPI 0: bf16 out (ldc stride). EPI 1: fp32 out = acc + bias + resid. EPI 2: bf16 gelu(acc+bias).
template <int EPI, int BM>
__global__ __launch_bounds__(256, BM == 128 ? 2 : 3)
void gemm_bt(const u16* __restrict__ A, const u16* __restrict__ BT,
             const float* __restrict__ bias, const float* resid,
             void* outp, int M, int N, int K, int ldc) {
  constexpr int NI = (BM == 128) ? 4 : 2;
  __shared__ u16 As[BM * 32];
  __shared__ u16 Bs[128 * 32];
  const int tid = threadIdx.x;
  const int lane = tid & 63, w = tid >> 6;
  const int row0 = blockIdx.y * BM, col0 = blockIdx.x * 128;
  const int wm = (BM == 128) ? (w >> 1) * 64 : 0;
  const int wn = (BM == 128) ? (w & 1) * 64 : w * 32;
  const int lr = lane & 15, lk = (lane >> 4) * 8;
  const int srow = lane >> 2, scol = (lane & 3) * 8;

  f32x4 acc[4][NI] = {};

  for (int k0 = 0; k0 < K; k0 += 32) {
    if (BM == 128) {
#pragma unroll
      for (int i = 0; i < 2; ++i) {
        const int chunk = w * 2 + i;
        load_lds16(A + (size_t)(row0 + chunk * 16 + srow) * K + k0 + scol, &As[chunk * 512]);
        load_lds16(BT + (size_t)(col0 + chunk * 16 + srow) * K + k0 + scol, &Bs[chunk * 512]);
      }
    } else {
      load_lds16(A + (size_t)(row0 + w * 16 + srow) * K + k0 + scol, &As[w * 512]);
#pragma unroll
      for (int i = 0; i < 2; ++i) {
        const int chunk = w * 2 + i;
        load_lds16(BT + (size_t)(col0 + chunk * 16 + srow) * K + k0 + scol, &Bs[chunk * 512]);
      }
    }
    __syncthreads();
    bf16x8 af[4], bf[NI];
#pragma unroll
    for (int mi = 0; mi < 4; ++mi) af[mi] = *(const bf16x8*)&As[(wm + mi * 16 + lr) * 32 + lk];
#pragma unroll
    for (int ni = 0; ni < NI; ++ni) bf[ni] = *(const bf16x8*)&Bs[(wn + ni * 16 + lr) * 32 + lk];
#pragma unroll
    for (int mi = 0; mi < 4; ++mi)
#pragma unroll
      for (int ni = 0; ni < NI; ++ni)
        acc[mi][ni] = mfma16(af[mi], bf[ni], acc[mi][ni]);
    __syncthreads();
  }

  const int rbase = (lane >> 4) * 4;
#pragma unroll
  for (int mi = 0; mi < 4; ++mi) {
#pragma unroll
    for (int ni = 0; ni < NI; ++ni) {
#pragma unroll
      for (int rr = 0; rr < 4; ++rr) {
        const int r = row0 + wm + mi * 16 + rbase + rr;
        const int c = col0 + wn + ni * 16 + lr;
        float v = acc[mi][ni][rr];
        if (EPI == 0) {
          ((u16*)outp)[(size_t)r * ldc + c] = cvt(v);
        } else if (EPI == 1) {
          ((float*)outp)[(size_t)r * ldc + c] = v + bias[c] + resid[(size_t)r * ldc + c];
        } else {
          v += bias[c];
          v = 0.5f * v * (1.f + erff(v * 0.70710678118654752f));
          ((u16*)outp)[(size_t)r * ldc + c] = cvt(v);
        }
      }
    }
  }
}

// ---------------- Flash attention (QBLK=128: 2 q-groups per wave) ----------------
// qk: [8192][1536] bf16 (q at col h*64, k at col 768+h*64), vt: [768][8192] bf16 (V^T, row h*64+d)
// out: [8192][768] bf16
__global__ __launch_bounds__(256, 2)
void flash_attn(const u16* __restrict__ qk, const u16* __restrict__ vt, u16* __restrict__ out) {
  __shared__ u16 Ks[2][64 * 64];  // K tile [kv][d], chunk-swizzled, double-buffered
  __shared__ u16 Vs[2][64 * 64];  // V^T tile [d][kv], chunk-swizzled, double-buffered
  __shared__ u16 Os[16 * 64];     // ones tile (rowsum-via-MFMA)
  __shared__ u16 P[128 * 72];     // P [qrow][kv], stride 72, per-warp private rows
  const int tid = threadIdx.x, lane = tid & 63, w = tid >> 6;
  const int b = blockIdx.z, h = blockIdx.y, qb = blockIdx.x;
  const u16* qp = qk + (size_t)b * 2048 * 1536 + h * 64;
  const u16* kp = qp + 768;
  const u16* vtp = vt + (size_t)(h * 64) * 8192 + b * 2048;
  const int lr = lane & 15, g = lane >> 4, lk = g * 8;
  const int qrow = qb * 128 + w * 32;

  // ones tile init (bf16 1.0 pairs)
  {
    unsigned* p32 = (unsigned*)Os;
    p32[tid] = 0x3f803f80u;
    p32[tid + 256] = 0x3f803f80u;
  }

  // Q fragments for 2 q-groups, pre-scaled by 0.125 * log2(e) (exp2 domain)
  bf16x8 qf[2][2];
#pragma unroll
  for (int gq = 0; gq < 2; ++gq) {
#pragma unroll
    for (int t = 0; t < 2; ++t) {
      s16x8 qr = *(const s16x8*)&qp[(size_t)(qrow + gq * 16 + lr) * 1536 + t * 32 + lk];
      bf16x8 f;
#pragma unroll
      for (int j = 0; j < 8; ++j) {
        unsigned u = (unsigned)(u16)qr[j] << 16;
        f[j] = (__bf16)(__uint_as_float(u) * 0.18033688f);
      }
      qf[gq][t] = f;
    }
  }

  f32x4 o[2][5] = {};  // [gq][0..3]: output d-tiles; [gq][4]: row-sum (ones column)
  float rowm[2][4];
#pragma unroll
  for (int gq = 0; gq < 2; ++gq)
#pragma unroll
    for (int rr = 0; rr < 4; ++rr) rowm[gq][rr] = -1e30f;

#define STAGE(bi, kv)                                                          \
  do {                                                                         \
    _Pragma("unroll") for (int i_ = 0; i_ < 2; ++i_) {                         \
      const int ch = i_ * 256 + tid;                                           \
      const int r_ = ch >> 3, c_ = ch & 7, cs_ = c_ ^ (r_ & 7);                \
      load_lds16(kp + (size_t)((kv) + r_) * 1536 + cs_ * 8, &Ks[bi][ch * 8]);  \
      load_lds16(vtp + (size_t)r_ * 8192 + (kv) + cs_ * 8, &Vs[bi][ch * 8]);   \
    }                                                                          \
  } while (0)

  STAGE(0, 0);
  __syncthreads();
  int cur = 0;

  for (int kv0 = 0; kv0 < 2048; kv0 += 64) {
    if (kv0 + 64 < 2048) STAGE(cur ^ 1, kv0 + 64);  // prefetch next tile; lands by the barrier

    // QK^T for both q-groups: each K fragment read feeds 2 MFMAs
    f32x4 s[2][4] = {};
#pragma unroll
    for (int t = 0; t < 2; ++t) {
#pragma unroll
      for (int ni = 0; ni < 4; ++ni) {
        const int r = ni * 16 + lr;
        bf16x8 kf = *(const bf16x8*)&Ks[cur][r * 64 + ((4 * t + g) ^ (lr & 7)) * 8];
        s[0][ni] = mfma16(qf[0][t], kf, s[0][ni]);
        s[1][ni] = mfma16(qf[1][t], kf, s[1][ni]);
      }
    }

    // defer-max: shfl-free common path; joint wave-uniform branch for both groups
    float lm[2][4];
#pragma unroll
    for (int gq = 0; gq < 2; ++gq)
#pragma unroll
      for (int rr = 0; rr < 4; ++rr)
        lm[gq][rr] = fmaxf(fmaxf(s[gq][0][rr], s[gq][1][rr]), fmaxf(s[gq][2][rr], s[gq][3][rr]));
    int ok = 1;
#pragma unroll
    for (int gq = 0; gq < 2; ++gq)
#pragma unroll
      for (int rr = 0; rr < 4; ++rr) ok &= (lm[gq][rr] <= rowm[gq][rr] + 8.f);
    if (!__all(ok)) {
#pragma unroll
      for (int gq = 0; gq < 2; ++gq) {
        float alpha[4];
#pragma unroll
        for (int rr = 0; rr < 4; ++rr) {
          float v = lm[gq][rr];
          v = fmaxf(v, __shfl_xor(v, 1));
          v = fmaxf(v, __shfl_xor(v, 2));
          v = fmaxf(v, __shfl_xor(v, 4));
          v = fmaxf(v, __shfl_xor(v, 8));
          const float mn = fmaxf(rowm[gq][rr], v);
          alpha[rr] = fexp2(rowm[gq][rr] - mn);
          rowm[gq][rr] = mn;
        }
#pragma unroll
        for (int di = 0; di < 5; ++di)
#pragma unroll
          for (int rr = 0; rr < 4; ++rr) o[gq][di][rr] *= alpha[rr];
      }
    }

    // P = exp2(S - rowm), bf16, staged to per-warp LDS rows (same-wave write->read)
#pragma unroll
    for (int gq = 0; gq < 2; ++gq) {
      const int prow = w * 32 + gq * 16 + g * 4;
#pragma unroll
      for (int ni = 0; ni < 4; ++ni)
#pragma unroll
        for (int rr = 0; rr < 4; ++rr)
          P[(prow + rr) * 72 + ni * 16 + lr] = cvt(fexp2(s[gq][ni][rr] - rowm[gq][rr]));
    }

    // PV: each V fragment read feeds 2 MFMAs; di=4 row-sum against ones tile
#pragma unroll
    for (int t = 0; t < 2; ++t) {
      bf16x8 pa0 = *(const bf16x8*)&P[(w * 32 + lr) * 72 + t * 32 + lk];
      bf16x8 pa1 = *(const bf16x8*)&P[(w * 32 + 16 + lr) * 72 + t * 32 + lk];
#pragma unroll
      for (int di = 0; di < 4; ++di) {
        bf16x8 vb = *(const bf16x8*)&Vs[cur][(di * 16 + lr) * 64 + ((4 * t + g) ^ (lr & 7)) * 8];
        o[0][di] = mfma16(pa0, vb, o[0][di]);
        o[1][di] = mfma16(pa1, vb, o[1][di]);
      }
      bf16x8 ob = *(const bf16x8*)&Os[lr * 64 + ((4 * t + g) ^ (lr & 7)) * 8];
      o[0][4] = mfma16(pa0, ob, o[0][4]);
      o[1][4] = mfma16(pa1, ob, o[1][4]);
    }

    __syncthreads();  // drains prefetch (vmcnt) + all waves done reading buf[cur]
    cur ^= 1;
  }
#undef STAGE

  const int rbase = g * 4;
#pragma unroll
  for (int gq = 0; gq < 2; ++gq) {
    float inv[4];
#pragma unroll
    for (int rr = 0; rr < 4; ++rr) inv[rr] = 1.0f / o[gq][4][rr];
#pragma unroll
    for (int di = 0; di < 4; ++di) {
#pragma unroll
      for (int rr = 0; rr < 4; ++rr) {
        const int n = qrow + gq * 16 + rbase + rr;
        out[((size_t)b * 2048 + n) * 768 + h * 64 + di * 16 + lr] = cvt(o[gq][di][rr] * inv[rr]);
      }
    }
  }
}

extern "C" void kernel_launch(void* const* d_in, const int* in_sizes, int n_in,
                              void* d_out, int out_size, void* d_ws, size_t ws_size,
                              hipStream_t stream) {
  const float* x     = (const float*)d_in[0];
  const float* y     = (const float*)d_in[1];
  const float* g1    = (const float*)d_in[4];
  const float* be1   = (const float*)d_in[5];
  const float* g2    = (const float*)d_in[6];
  const float* be2   = (const float*)d_in[7];
  const float* g3    = (const float*)d_in[8];
  const float* be3   = (const float*)d_in[9];
  const float* gy    = (const float*)d_in[10];
  const float* bey   = (const float*)d_in[11];
  const float* Wqkv  = (const float*)d_in[12];
  const float* Wo_sa = (const float*)d_in[13];
  const float* bo_sa = (const float*)d_in[14];
  const float* Wq    = (const float*)d_in[15];
  const float* Wk    = (const float*)d_in[16];
  const float* Wv    = (const float*)d_in[17];
  const float* Wo_ca = (const float*)d_in[18];
  const float* bo_ca = (const float*)d_in[19];
  const float* W1    = (const float*)d_in[20];
  const float* b1    = (const float*)d_in[21];
  const float* W2    = (const float*)d_in[22];
  const float* b2    = (const float*)d_in[23];

  // workspace (u16 units), total 94.4 MB
  u16* WqkvT = (u16*)d_ws;                        // [2304][768]
  u16* WoSaT = WqkvT + (size_t)2304 * 768;        // [768][768]
  u16* WqT   = WoSaT + (size_t)768 * 768;
  u16* WkT   = WqT   + (size_t)768 * 768;
  u16* WvT   = WkT   + (size_t)768 * 768;
  u16* WoCaT = WvT   + (size_t)768 * 768;
  u16* W1T   = WoCaT + (size_t)768 * 768;         // [3072][768]
  u16* W2T   = W1T   + (size_t)3072 * 768;        // [768][3072]
  u16* R1    = W2T   + (size_t)768 * 3072;        // [8192][3072]: qk [8192][1536] / mlp hidden
  u16* VT    = R1    + (size_t)8192 * 1536;       // [768][8192] V^T (upper half of R1 region)
  u16* R2    = R1    + (size_t)8192 * 3072;       // [8192][768]
  u16* R3    = R2    + (size_t)8192 * 768;        // [8192][768]
  float* xo  = (float*)d_out;                     // fp32 residual spine x1/x2/out

  WT8 wa;
  {
    const float* s8[8] = {Wqkv, Wo_sa, Wq, Wk, Wv, Wo_ca, W1, W2};
    u16* d8[8] = {WqkvT, WoSaT, WqT, WkT, WvT, WoCaT, W1T, W2T};
    const int K8[8] = {768, 768, 768, 768, 768, 768, 768, 3072};
    const int N8[8] = {2304, 768, 768, 768, 768, 768, 3072, 768};
    for (int i = 0; i < 8; ++i) {
      wa.src[i] = s8[i]; wa.dst[i] = d8[i];
      wa.K[i] = K8[i]; wa.N[i] = N8[i];
      wa.cnt[i] = (N8[i] / 32) * (K8[i] / 32);
    }
  }
  wtrans_all<<<9216, dim3(32, 8), 0, stream>>>(wa);

  // --- self attention ---
  ln_bf16<<<8192, 256, 0, stream>>>(x, g1, be1, R2);
  gemm_bt<0, 128><<<dim3(12, 64), 256, 0, stream>>>(R2, WqkvT, nullptr, nullptr, R1, 8192, 1536, 768, 1536);
  gemm_bt<0, 64><<<dim3(64, 12), 256, 0, stream>>>(WqkvT + (size_t)1536 * 768, R2, nullptr, nullptr, VT, 768, 8192, 768, 8192);
  flash_attn<<<dim3(16, 12, 4), 256, 0, stream>>>(R1, VT, R2);
  gemm_bt<1, 64><<<dim3(6, 128), 256, 0, stream>>>(R2, WoSaT, bo_sa, x, xo, 8192, 768, 768, 768);

  // --- cross attention ---
  ln_bf16<<<8192, 256, 0, stream>>>(y, gy, bey, R3);
  ln_bf16<<<8192, 256, 0, stream>>>(xo, g2, be2, R2);
  gemm_bt<0, 64><<<dim3(6, 128), 256, 0, stream>>>(R2, WqT, nullptr, nullptr, R1, 8192, 768, 768, 1536);
  gemm_bt<0, 64><<<dim3(6, 128), 256, 0, stream>>>(R3, WkT, nullptr, nullptr, R1 + 768, 8192, 768, 768, 1536);
  gemm_bt<0, 64><<<dim3(64, 12), 256, 0, stream>>>(WvT, R3, nullptr, nullptr, VT, 768, 8192, 768, 8192);
  flash_attn<<<dim3(16, 12, 4), 256, 0, stream>>>(R1, VT, R3);
  gemm_bt<1, 64><<<dim3(6, 128), 256, 0, stream>>>(R3, WoCaT, bo_ca, xo, xo, 8192, 768, 768, 768);

  // --- MLP ---
  ln_bf16<<<8192, 256, 0, stream>>>(xo, g3, be3, R2);
  gemm_bt<2, 128><<<dim3(24, 64), 256, 0, stream>>>(R2, W1T, b1, nullptr, R1, 8192, 3072, 768, 3072);
  gemm_bt<1, 64><<<dim3(6, 128), 256, 0, stream>>>(R1, W2T, b2, xo, xo, 8192, 768, 3072, 768);
}

// Round 12
// 515.661 us; speedup vs baseline: 1.1032x; 1.0358x over previous
//
#include <hip/hip_runtime.h>
#include <math.h>

typedef unsigned short u16;
typedef __attribute__((ext_vector_type(4))) float f32x4;
typedef __attribute__((ext_vector_type(8))) __bf16 bf16x8;
typedef __attribute__((ext_vector_type(8))) short s16x8;

#define AS1 __attribute__((address_space(1)))
#define AS3 __attribute__((address_space(3)))

__device__ __forceinline__ u16 cvt(float f) {
  __bf16 h = (__bf16)f;
  return *(u16*)&h;
}

__device__ __forceinline__ unsigned cvtpk(float lo, float hi) {
  unsigned r;
  asm("v_cvt_pk_bf16_f32 %0, %1, %2" : "=v"(r) : "v"(lo), "v"(hi));
  return r;
}

__device__ __forceinline__ float fexp2(float x) {
  float r;
  asm volatile("v_exp_f32 %0, %1" : "=v"(r) : "v"(x));
  return r;
}

__device__ __forceinline__ void load_lds16(const void* g, void* l) {
  __builtin_amdgcn_global_load_lds((AS1 void*)g, (AS3 void*)l, 16, 0, 0);
}

__device__ __forceinline__ f32x4 mfma16(bf16x8 a, bf16x8 b, f32x4 c) {
  return __builtin_amdgcn_mfma_f32_16x16x32_bf16(a, b, c, 0, 0, 0);
}

// ---------------- merged weight transpose fp32 -> bf16, W[K][N] -> WT[N][K] ----------------
struct WT8 {
  const float* src[8];
  u16* dst[8];
  int K[8];
  int N[8];
  int cnt[8];  // (N/32)*(K/32)
};

__global__ void wtrans_all(WT8 a) {
  __shared__ float t[32][33];
  int rem = blockIdx.x, i = 0;
  while (rem >= a.cnt[i]) { rem -= a.cnt[i]; ++i; }
  const int nb = a.N[i] >> 5;
  const int n0 = (rem % nb) * 32, k0 = (rem / nb) * 32;
  const float* W = a.src[i];
  u16* WT = a.dst[i];
  const int K = a.K[i], N = a.N[i];
  for (int r = threadIdx.y; r < 32; r += 8)
    t[r][threadIdx.x] = W[(size_t)(k0 + r) * N + n0 + threadIdx.x];
  __syncthreads();
  for (int r = threadIdx.y; r < 32; r += 8)
    WT[(size_t)(n0 + r) * K + k0 + threadIdx.x] = cvt(t[threadIdx.x][r]);
}

// ---------------- LayerNorm fp32 -> bf16 (row = 768) ----------------
__global__ __launch_bounds__(256)
void ln_bf16(const float* __restrict__ in, const float* __restrict__ g,
             const float* __restrict__ be, u16* __restrict__ out) {
  const int row = blockIdx.x, tid = threadIdx.x;
  const float* x = in + (size_t)row * 768;
  float v0 = x[tid], v1 = x[tid + 256], v2 = x[tid + 512];
  float s = v0 + v1 + v2;
  for (int m = 1; m < 64; m <<= 1) s += __shfl_xor(s, m);
  __shared__ float red[8];
  const int w = tid >> 6, lane = tid & 63;
  if (lane == 0) red[w] = s;
  __syncthreads();
  s = red[0] + red[1] + red[2] + red[3];
  const float mean = s * (1.f / 768.f);
  const float d0 = v0 - mean, d1 = v1 - mean, d2 = v2 - mean;
  float q = d0 * d0 + d1 * d1 + d2 * d2;
  for (int m = 1; m < 64; m <<= 1) q += __shfl_xor(q, m);
  if (lane == 0) red[4 + w] = q;
  __syncthreads();
  q = red[4] + red[5] + red[6] + red[7];
  const float rstd = rsqrtf(q * (1.f / 768.f) + 1e-5f);
  u16* o = out + (size_t)row * 768;
  o[tid]       = cvt(d0 * rstd * g[tid]       + be[tid]);
  o[tid + 256] = cvt(d1 * rstd * g[tid + 256] + be[tid + 256]);
  o[tid + 512] = cvt(d2 * rstd * g[tid + 512] + be[tid + 512]);
}

// ---------------- GEMM: C[M][N] = A[M][K] * BT[N][K]^T ----------------
// BM=128: 4 waves, 64x64 each (big GEMMs). BM=64: 4 waves, 64x32 each (grid-starved GEMMs).
// EPI 0: bf16 out (ldc stride). EPI 1: fp32 out = acc + bias + resid. EPI 2: bf16 gelu(acc+bias).
template <int EPI, int BM>
__global__ __launch_bounds__(256, BM == 128 ? 2 : 3)
void gemm_bt(const u16* __restrict__ A, const u16* __restrict__ BT,
             const float* __restrict__ bias, const float* resid,
             void* outp, int M, int N, int K, int ldc) {
  constexpr int NI = (BM == 128) ? 4 : 2;
  __shared__ u16 As[BM * 32];
  __shared__ u16 Bs[128 * 32];
  const int tid = threadIdx.x;
  const int lane = tid & 63, w = tid >> 6;
  const int row0 = blockIdx.y * BM, col0 = blockIdx.x * 128;
  const int wm = (BM == 128) ? (w >> 1) * 64 : 0;
  const int wn = (BM == 128) ? (w & 1) * 64 : w * 32;
  const int lr = lane & 15, lk = (lane >> 4) * 8;
  const int srow = lane >> 2, scol = (lane & 3) * 8;

  f32x4 acc[4][NI] = {};

  for (int k0 = 0; k0 < K; k0 += 32) {
    if (BM == 128) {
#pragma unroll
      for (int i = 0; i < 2; ++i) {
        const int chunk = w * 2 + i;
        load_lds16(A + (size_t)(row0 + chunk * 16 + srow) * K + k0 + scol, &As[chunk * 512]);
        load_lds16(BT + (size_t)(col0 + chunk * 16 + srow) * K + k0 + scol, &Bs[chunk * 512]);
      }
    } else {
      load_lds16(A + (size_t)(row0 + w * 16 + srow) * K + k0 + scol, &As[w * 512]);
#pragma unroll
      for (int i = 0; i < 2; ++i) {
        const int chunk = w * 2 + i;
        load_lds16(BT + (size_t)(col0 + chunk * 16 + srow) * K + k0 + scol, &Bs[chunk * 512]);
      }
    }
    __syncthreads();
    bf16x8 af[4], bf[NI];
#pragma unroll
    for (int mi = 0; mi < 4; ++mi) af[mi] = *(const bf16x8*)&As[(wm + mi * 16 + lr) * 32 + lk];
#pragma unroll
    for (int ni = 0; ni < NI; ++ni) bf[ni] = *(const bf16x8*)&Bs[(wn + ni * 16 + lr) * 32 + lk];
#pragma unroll
    for (int mi = 0; mi < 4; ++mi)
#pragma unroll
      for (int ni = 0; ni < NI; ++ni)
        acc[mi][ni] = mfma16(af[mi], bf[ni], acc[mi][ni]);
    __syncthreads();
  }

  const int rbase = (lane >> 4) * 4;
#pragma unroll
  for (int mi = 0; mi < 4; ++mi) {
#pragma unroll
    for (int ni = 0; ni < NI; ++ni) {
#pragma unroll
      for (int rr = 0; rr < 4; ++rr) {
        const int r = row0 + wm + mi * 16 + rbase + rr;
        const int c = col0 + wn + ni * 16 + lr;
        float v = acc[mi][ni][rr];
        if (EPI == 0) {
          ((u16*)outp)[(size_t)r * ldc + c] = cvt(v);
        } else if (EPI == 1) {
          ((float*)outp)[(size_t)r * ldc + c] = v + bias[c] + resid[(size_t)r * ldc + c];
        } else {
          v += bias[c];
          v = 0.5f * v * (1.f + erff(v * 0.70710678118654752f));
          ((u16*)outp)[(size_t)r * ldc + c] = cvt(v);
        }
      }
    }
  }
}

// ---------------- Flash attention (swapped QK^T: q in C-columns) ----------------
// qk: [8192][1536] bf16 (q at col h*64, k at col 768+h*64), vt: [768][8192] bf16 (V^T, row h*64+d)
// out: [8192][768] bf16
__global__ __launch_bounds__(256, 3)
void flash_attn(const u16* __restrict__ qk, const u16* __restrict__ vt, u16* __restrict__ out) {
  __shared__ u16 Ks[2][64 * 64];  // K tile [kv][d], chunk-swizzled, double-buffered
  __shared__ u16 Vs[2][64 * 64];  // V^T tile [d][kv], chunk-swizzled, double-buffered
  __shared__ u16 P[128 * 72];     // P [qrow][kv], stride 72, per-warp private rows
  const int tid = threadIdx.x, lane = tid & 63, w = tid >> 6;
  const int b = blockIdx.z, h = blockIdx.y, qb = blockIdx.x;
  const u16* qp = qk + (size_t)b * 2048 * 1536 + h * 64;
  const u16* kp = qp + 768;
  const u16* vtp = vt + (size_t)(h * 64) * 8192 + b * 2048;
  const int lr = lane & 15, g = lane >> 4, lk = g * 8;
  const int qrow = qb * 128 + w * 32;

  // Q fragments for 2 q-groups, pre-scaled by 0.125 * log2(e) (exp2 domain); used as B operand.
  bf16x8 qf[2][2];
#pragma unroll
  for (int gq = 0; gq < 2; ++gq) {
#pragma unroll
    for (int t = 0; t < 2; ++t) {
      s16x8 qr = *(const s16x8*)&qp[(size_t)(qrow + gq * 16 + lr) * 1536 + t * 32 + lk];
      bf16x8 f;
#pragma unroll
      for (int j = 0; j < 8; ++j) {
        unsigned u = (unsigned)(u16)qr[j] << 16;
        f[j] = (__bf16)(__uint_as_float(u) * 0.18033688f);
      }
      qf[gq][t] = f;
    }
  }

  // constant ones A-fragment for rowsum-via-MFMA
  bf16x8 onesf;
#pragma unroll
  for (int j = 0; j < 8; ++j) onesf[j] = (__bf16)1.0f;

  f32x4 o[2][4] = {};  // [gq][di]: O^T tiles, row=d, col=q
  f32x4 o4[2] = {};    // row-sum accumulators (every row = column sum)
  float rowm[2] = {-1e30f, -1e30f};

#define STAGE(bi, kv)                                                          \
  do {                                                                         \
    _Pragma("unroll") for (int i_ = 0; i_ < 2; ++i_) {                         \
      const int ch = i_ * 256 + tid;                                           \
      const int r_ = ch >> 3, c_ = ch & 7, cs_ = c_ ^ (r_ & 7);                \
      load_lds16(kp + (size_t)((kv) + r_) * 1536 + cs_ * 8, &Ks[bi][ch * 8]);  \
      load_lds16(vtp + (size_t)r_ * 8192 + (kv) + cs_ * 8, &Vs[bi][ch * 8]);   \
    }                                                                          \
  } while (0)

  STAGE(0, 0);
  __syncthreads();
  int cur = 0;

  for (int kv0 = 0; kv0 < 2048; kv0 += 64) {
    if (kv0 + 64 < 2048) STAGE(cur ^ 1, kv0 + 64);  // prefetch next tile; lands by the barrier

    // swapped QK^T: S^T[kv][q]; lane holds 16 kv-scores for one q
    f32x4 s[2][4] = {};
#pragma unroll
    for (int t = 0; t < 2; ++t) {
#pragma unroll
      for (int ni = 0; ni < 4; ++ni) {
        const int r = ni * 16 + lr;
        bf16x8 kf = *(const bf16x8*)&Ks[cur][r * 64 + ((4 * t + g) ^ (lr & 7)) * 8];
        s[0][ni] = mfma16(kf, qf[0][t], s[0][ni]);
        s[1][ni] = mfma16(kf, qf[1][t], s[1][ni]);
      }
    }

    // defer-max: lane-local max over 16 values per gq; shfl-free common path
    float lm[2];
#pragma unroll
    for (int gq = 0; gq < 2; ++gq) {
      float m0 = fmaxf(fmaxf(s[gq][0][0], s[gq][0][1]), fmaxf(s[gq][0][2], s[gq][0][3]));
      float m1 = fmaxf(fmaxf(s[gq][1][0], s[gq][1][1]), fmaxf(s[gq][1][2], s[gq][1][3]));
      float m2 = fmaxf(fmaxf(s[gq][2][0], s[gq][2][1]), fmaxf(s[gq][2][2], s[gq][2][3]));
      float m3 = fmaxf(fmaxf(s[gq][3][0], s[gq][3][1]), fmaxf(s[gq][3][2], s[gq][3][3]));
      lm[gq] = fmaxf(fmaxf(m0, m1), fmaxf(m2, m3));
    }
    const int ok = (lm[0] <= rowm[0] + 8.f) & (lm[1] <= rowm[1] + 8.f);
    if (!__all(ok)) {
#pragma unroll
      for (int gq = 0; gq < 2; ++gq) {
        float v = lm[gq];
        v = fmaxf(v, __shfl_xor(v, 16));
        v = fmaxf(v, __shfl_xor(v, 32));
        const float mn = fmaxf(rowm[gq], v);
        const float alpha = fexp2(rowm[gq] - mn);
        rowm[gq] = mn;
#pragma unroll
        for (int di = 0; di < 4; ++di) o[gq][di] *= alpha;
        o4[gq] *= alpha;
      }
    }

    // P = exp2(S - rowm), packed bf16 pairs, b32 writes to per-warp LDS rows
    unsigned* Pw = (unsigned*)P;
#pragma unroll
    for (int gq = 0; gq < 2; ++gq) {
      const int qrl = w * 32 + gq * 16 + lr;
#pragma unroll
      for (int ni = 0; ni < 4; ++ni) {
#pragma unroll
        for (int r = 0; r < 2; ++r) {
          const float p0 = fexp2(s[gq][ni][2 * r] - rowm[gq]);
          const float p1 = fexp2(s[gq][ni][2 * r + 1] - rowm[gq]);
          Pw[(qrl * 72 + ni * 16 + 4 * g + 2 * r) >> 1] = cvtpk(p0, p1);
        }
      }
    }

    // PV: O^T += V^T * P (A = V^T tile, B = P rows); ones-A accumulates row sums
#pragma unroll
    for (int t = 0; t < 2; ++t) {
      bf16x8 pb0 = *(const bf16x8*)&P[(w * 32 + lr) * 72 + t * 32 + g * 8];
      bf16x8 pb1 = *(const bf16x8*)&P[(w * 32 + 16 + lr) * 72 + t * 32 + g * 8];
#pragma unroll
      for (int di = 0; di < 4; ++di) {
        bf16x8 va = *(const bf16x8*)&Vs[cur][(di * 16 + lr) * 64 + ((4 * t + g) ^ (lr & 7)) * 8];
        o[0][di] = mfma16(va, pb0, o[0][di]);
        o[1][di] = mfma16(va, pb1, o[1][di]);
      }
      o4[0] = mfma16(onesf, pb0, o4[0]);
      o4[1] = mfma16(onesf, pb1, o4[1]);
    }

    __syncthreads();  // drains prefetch (vmcnt) + all waves done reading buf[cur]
    cur ^= 1;
  }
#undef STAGE

  // epilogue: normalize and store; lane's 4 rr values are d-contiguous -> packed 8B stores
#pragma unroll
  for (int gq = 0; gq < 2; ++gq) {
    const float inv = 1.0f / o4[gq][0];
    const size_t n = (size_t)b * 2048 + qrow + gq * 16 + lr;
#pragma unroll
    for (int di = 0; di < 4; ++di) {
      uint2 uv;
      uv.x = cvtpk(o[gq][di][0] * inv, o[gq][di][1] * inv);
      uv.y = cvtpk(o[gq][di][2] * inv, o[gq][di][3] * inv);
      *(uint2*)&out[n * 768 + h * 64 + di * 16 + 4 * g] = uv;
    }
  }
}

extern "C" void kernel_launch(void* const* d_in, const int* in_sizes, int n_in,
                              void* d_out, int out_size, void* d_ws, size_t ws_size,
                              hipStream_t stream) {
  const float* x     = (const float*)d_in[0];
  const float* y     = (const float*)d_in[1];
  const float* g1    = (const float*)d_in[4];
  const float* be1   = (const float*)d_in[5];
  const float* g2    = (const float*)d_in[6];
  const float* be2   = (const float*)d_in[7];
  const float* g3    = (const float*)d_in[8];
  const float* be3   = (const float*)d_in[9];
  const float* gy    = (const float*)d_in[10];
  const float* bey   = (const float*)d_in[11];
  const float* Wqkv  = (const float*)d_in[12];
  const float* Wo_sa = (const float*)d_in[13];
  const float* bo_sa = (const float*)d_in[14];
  const float* Wq    = (const float*)d_in[15];
  const float* Wk    = (const float*)d_in[16];
  const float* Wv    = (const float*)d_in[17];
  const float* Wo_ca = (const float*)d_in[18];
  const float* bo_ca = (const float*)d_in[19];
  const float* W1    = (const float*)d_in[20];
  const float* b1    = (const float*)d_in[21];
  const float* W2    = (const float*)d_in[22];
  const float* b2    = (const float*)d_in[23];

  // workspace (u16 units), total 94.4 MB
  u16* WqkvT = (u16*)d_ws;                        // [2304][768]
  u16* WoSaT = WqkvT + (size_t)2304 * 768;        // [768][768]
  u16* WqT   = WoSaT + (size_t)768 * 768;
  u16* WkT   = WqT   + (size_t)768 * 768;
  u16* WvT   = WkT   + (size_t)768 * 768;
  u16* WoCaT = WvT   + (size_t)768 * 768;
  u16* W1T   = WoCaT + (size_t)768 * 768;         // [3072][768]
  u16* W2T   = W1T   + (size_t)3072 * 768;        // [768][3072]
  u16* R1    = W2T   + (size_t)768 * 3072;        // [8192][3072]: qk [8192][1536] / mlp hidden
  u16* VT    = R1    + (size_t)8192 * 1536;       // [768][8192] V^T (upper half of R1 region)
  u16* R2    = R1    + (size_t)8192 * 3072;       // [8192][768]
  u16* R3    = R2    + (size_t)8192 * 768;        // [8192][768]
  float* xo  = (float*)d_out;                     // fp32 residual spine x1/x2/out

  WT8 wa;
  {
    const float* s8[8] = {Wqkv, Wo_sa, Wq, Wk, Wv, Wo_ca, W1, W2};
    u16* d8[8] = {WqkvT, WoSaT, WqT, WkT, WvT, WoCaT, W1T, W2T};
    const int K8[8] = {768, 768, 768, 768, 768, 768, 768, 3072};
    const int N8[8] = {2304, 768, 768, 768, 768, 768, 3072, 768};
    for (int i = 0; i < 8; ++i) {
      wa.src[i] = s8[i]; wa.dst[i] = d8[i];
      wa.K[i] = K8[i]; wa.N[i] = N8[i];
      wa.cnt[i] = (N8[i] / 32) * (K8[i] / 32);
    }
  }
  wtrans_all<<<9216, dim3(32, 8), 0, stream>>>(wa);

  // --- self attention ---
  ln_bf16<<<8192, 256, 0, stream>>>(x, g1, be1, R2);
  gemm_bt<0, 128><<<dim3(12, 64), 256, 0, stream>>>(R2, WqkvT, nullptr, nullptr, R1, 8192, 1536, 768, 1536);
  gemm_bt<0, 64><<<dim3(64, 12), 256, 0, stream>>>(WqkvT + (size_t)1536 * 768, R2, nullptr, nullptr, VT, 768, 8192, 768, 8192);
  flash_attn<<<dim3(16, 12, 4), 256, 0, stream>>>(R1, VT, R2);
  gemm_bt<1, 64><<<dim3(6, 128), 256, 0, stream>>>(R2, WoSaT, bo_sa, x, xo, 8192, 768, 768, 768);

  // --- cross attention ---
  ln_bf16<<<8192, 256, 0, stream>>>(y, gy, bey, R3);
  ln_bf16<<<8192, 256, 0, stream>>>(xo, g2, be2, R2);
  gemm_bt<0, 64><<<dim3(6, 128), 256, 0, stream>>>(R2, WqT, nullptr, nullptr, R1, 8192, 768, 768, 1536);
  gemm_bt<0, 64><<<dim3(6, 128), 256, 0, stream>>>(R3, WkT, nullptr, nullptr, R1 + 768, 8192, 768, 768, 1536);
  gemm_bt<0, 64><<<dim3(64, 12), 256, 0, stream>>>(WvT, R3, nullptr, nullptr, VT, 768, 8192, 768, 8192);
  flash_attn<<<dim3(16, 12, 4), 256, 0, stream>>>(R1, VT, R3);
  gemm_bt<1, 64><<<dim3(6, 128), 256, 0, stream>>>(R3, WoCaT, bo_ca, xo, xo, 8192, 768, 768, 768);

  // --- MLP ---
  ln_bf16<<<8192, 256, 0, stream>>>(xo, g3, be3, R2);
  gemm_bt<2, 128><<<dim3(24, 64), 256, 0, stream>>>(R2, W1T, b1, nullptr, R1, 8192, 3072, 768, 3072);
  gemm_bt<1, 64><<<dim3(6, 128), 256, 0, stream>>>(R1, W2T, b2, xo, xo, 8192, 768, 3072, 768);
}

// Round 13
// 467.872 us; speedup vs baseline: 1.2159x; 1.1021x over previous
//
#include <hip/hip_runtime.h>
#include <math.h>

typedef unsigned short u16;
typedef __attribute__((ext_vector_type(4))) float f32x4;
typedef __attribute__((ext_vector_type(8))) __bf16 bf16x8;
typedef __attribute__((ext_vector_type(8))) short s16x8;

#define AS1 __attribute__((address_space(1)))
#define AS3 __attribute__((address_space(3)))

__device__ __forceinline__ u16 cvt(float f) {
  __bf16 h = (__bf16)f;
  return *(u16*)&h;
}

__device__ __forceinline__ unsigned cvtpk(float lo, float hi) {
  unsigned r;
  asm("v_cvt_pk_bf16_f32 %0, %1, %2" : "=v"(r) : "v"(lo), "v"(hi));
  return r;
}

__device__ __forceinline__ float fexp2(float x) {
  float r;
  asm volatile("v_exp_f32 %0, %1" : "=v"(r) : "v"(x));
  return r;
}

__device__ __forceinline__ void load_lds16(const void* g, void* l) {
  __builtin_amdgcn_global_load_lds((AS1 void*)g, (AS3 void*)l, 16, 0, 0);
}

__device__ __forceinline__ f32x4 mfma16(bf16x8 a, bf16x8 b, f32x4 c) {
  return __builtin_amdgcn_mfma_f32_16x16x32_bf16(a, b, c, 0, 0, 0);
}

// ---------------- merged weight transpose fp32 -> bf16, W[K][N] -> WT[N][K] ----------------
struct WT8 {
  const float* src[8];
  u16* dst[8];
  int K[8];
  int N[8];
  int cnt[8];  // (N/32)*(K/32)
};

__global__ void wtrans_all(WT8 a) {
  __shared__ float t[32][33];
  int rem = blockIdx.x, i = 0;
  while (rem >= a.cnt[i]) { rem -= a.cnt[i]; ++i; }
  const int nb = a.N[i] >> 5;
  const int n0 = (rem % nb) * 32, k0 = (rem / nb) * 32;
  const float* W = a.src[i];
  u16* WT = a.dst[i];
  const int K = a.K[i], N = a.N[i];
  for (int r = threadIdx.y; r < 32; r += 8)
    t[r][threadIdx.x] = W[(size_t)(k0 + r) * N + n0 + threadIdx.x];
  __syncthreads();
  for (int r = threadIdx.y; r < 32; r += 8)
    WT[(size_t)(n0 + r) * K + k0 + threadIdx.x] = cvt(t[threadIdx.x][r]);
}

// ---------------- LayerNorm fp32 -> bf16 (row = 768) ----------------
__global__ __launch_bounds__(256)
void ln_bf16(const float* __restrict__ in, const float* __restrict__ g,
             const float* __restrict__ be, u16* __restrict__ out) {
  const int row = blockIdx.x, tid = threadIdx.x;
  const float* x = in + (size_t)row * 768;
  float v0 = x[tid], v1 = x[tid + 256], v2 = x[tid + 512];
  float s = v0 + v1 + v2;
  for (int m = 1; m < 64; m <<= 1) s += __shfl_xor(s, m);
  __shared__ float red[8];
  const int w = tid >> 6, lane = tid & 63;
  if (lane == 0) red[w] = s;
  __syncthreads();
  s = red[0] + red[1] + red[2] + red[3];
  const float mean = s * (1.f / 768.f);
  const float d0 = v0 - mean, d1 = v1 - mean, d2 = v2 - mean;
  float q = d0 * d0 + d1 * d1 + d2 * d2;
  for (int m = 1; m < 64; m <<= 1) q += __shfl_xor(q, m);
  if (lane == 0) red[4 + w] = q;
  __syncthreads();
  q = red[4] + red[5] + red[6] + red[7];
  const float rstd = rsqrtf(q * (1.f / 768.f) + 1e-5f);
  u16* o = out + (size_t)row * 768;
  o[tid]       = cvt(d0 * rstd * g[tid]       + be[tid]);
  o[tid + 256] = cvt(d1 * rstd * g[tid + 256] + be[tid + 256]);
  o[tid + 512] = cvt(d2 * rstd * g[tid + 512] + be[tid + 512]);
}

// ---------------- GEMM: C[M][N] = A[M][K] * BT[N][K]^T ----------------
// BM=128: BK=32, 4 waves 64x64 (big GEMMs).
// BM=64:  BK=64, XOR-swizzled LDS, XCD-chunked block swizzle, 4 waves 64x32 (skinny GEMMs).
// EPI 0: bf16 out (ldc stride). EPI 1: fp32 out = acc + bias + resid. EPI 2: bf16 gelu(acc+bias).
template <int EPI, int BM>
__global__ __launch_bounds__(256, BM == 128 ? 2 : 3)
void gemm_bt(const u16* __restrict__ A, const u16* __restrict__ BT,
             const float* __restrict__ bias, const float* resid,
             void* outp, int M, int N, int K, int ldc) {
  constexpr int NI = (BM == 128) ? 4 : 2;
  constexpr int BK = (BM == 128) ? 32 : 64;
  __shared__ u16 As[BM * BK];
  __shared__ u16 Bs[128 * BK];
  const int tid = threadIdx.x;
  const int lane = tid & 63, w = tid >> 6;
  const int lr = lane & 15, g = lane >> 4;

  int bx = blockIdx.x, by = blockIdx.y;
  if (BM == 64) {
    // bijective XCD-chunked swizzle: XCD k owns a contiguous logical chunk
    const int nwg = gridDim.x * gridDim.y;
    if ((nwg & 7) == 0) {
      const int d = by * gridDim.x + bx;
      const int l = (d & 7) * (nwg >> 3) + (d >> 3);
      bx = l % gridDim.x;
      by = l / gridDim.x;
    }
  }
  const int row0 = by * BM, col0 = bx * 128;
  const int wm = (BM == 128) ? (w >> 1) * 64 : 0;
  const int wn = (BM == 128) ? (w & 1) * 64 : w * 32;

  f32x4 acc[4][NI] = {};

  if (BM == 128) {
    const int srow = lane >> 2, scol = (lane & 3) * 8;
    const int lk = g * 8;
    for (int k0 = 0; k0 < K; k0 += 32) {
#pragma unroll
      for (int i = 0; i < 2; ++i) {
        const int chunk = w * 2 + i;
        load_lds16(A + (size_t)(row0 + chunk * 16 + srow) * K + k0 + scol, &As[chunk * 512]);
        load_lds16(BT + (size_t)(col0 + chunk * 16 + srow) * K + k0 + scol, &Bs[chunk * 512]);
      }
      __syncthreads();
      bf16x8 af[4], bf[NI];
#pragma unroll
      for (int mi = 0; mi < 4; ++mi) af[mi] = *(const bf16x8*)&As[(wm + mi * 16 + lr) * 32 + lk];
#pragma unroll
      for (int ni = 0; ni < NI; ++ni) bf[ni] = *(const bf16x8*)&Bs[(wn + ni * 16 + lr) * 32 + lk];
#pragma unroll
      for (int mi = 0; mi < 4; ++mi)
#pragma unroll
        for (int ni = 0; ni < NI; ++ni)
          acc[mi][ni] = mfma16(af[mi], bf[ni], acc[mi][ni]);
      __syncthreads();
    }
  } else {
    // BK=64, XOR chunk-swizzled staging (source-side) + matching XOR on fragment reads
    for (int k0 = 0; k0 < K; k0 += 64) {
#pragma unroll
      for (int i = 0; i < 2; ++i) {
        const int ch = i * 256 + tid;
        const int r = ch >> 3, c = ch & 7, cs = c ^ (r & 7);
        load_lds16(A + (size_t)(row0 + r) * K + k0 + cs * 8, &As[ch * 8]);
      }
#pragma unroll
      for (int i = 0; i < 4; ++i) {
        const int ch = i * 256 + tid;
        const int r = ch >> 3, c = ch & 7, cs = c ^ (r & 7);
        load_lds16(BT + (size_t)(col0 + r) * K + k0 + cs * 8, &Bs[ch * 8]);
      }
      __syncthreads();
#pragma unroll
      for (int kk = 0; kk < 2; ++kk) {
        bf16x8 af[4], bf[NI];
#pragma unroll
        for (int mi = 0; mi < 4; ++mi) {
          const int r = mi * 16 + lr;
          af[mi] = *(const bf16x8*)&As[r * 64 + (((kk * 4 + g) ^ (r & 7)) * 8)];
        }
#pragma unroll
        for (int ni = 0; ni < NI; ++ni) {
          const int r = wn + ni * 16 + lr;
          bf[ni] = *(const bf16x8*)&Bs[r * 64 + (((kk * 4 + g) ^ (r & 7)) * 8)];
        }
#pragma unroll
        for (int mi = 0; mi < 4; ++mi)
#pragma unroll
          for (int ni = 0; ni < NI; ++ni)
            acc[mi][ni] = mfma16(af[mi], bf[ni], acc[mi][ni]);
      }
      __syncthreads();
    }
  }

  const int rbase = g * 4;
#pragma unroll
  for (int mi = 0; mi < 4; ++mi) {
#pragma unroll
    for (int ni = 0; ni < NI; ++ni) {
#pragma unroll
      for (int rr = 0; rr < 4; ++rr) {
        const int r = row0 + wm + mi * 16 + rbase + rr;
        const int c = col0 + wn + ni * 16 + lr;
        float v = acc[mi][ni][rr];
        if (EPI == 0) {
          ((u16*)outp)[(size_t)r * ldc + c] = cvt(v);
        } else if (EPI == 1) {
          ((float*)outp)[(size_t)r * ldc + c] = v + bias[c] + resid[(size_t)r * ldc + c];
        } else {
          v += bias[c];
          v = 0.5f * v * (1.f + erff(v * 0.70710678118654752f));
          ((u16*)outp)[(size_t)r * ldc + c] = cvt(v);
        }
      }
    }
  }
}

// ---------------- Flash attention (swapped QK^T: q in C-columns) ----------------
// qk: [8192][1536] bf16 (q at col h*64, k at col 768+h*64), vt: [768][8192] bf16 (V^T, row h*64+d)
// out: [8192][768] bf16
__global__ __launch_bounds__(256, 3)
void flash_attn(const u16* __restrict__ qk, const u16* __restrict__ vt, u16* __restrict__ out) {
  __shared__ u16 Ks[2][64 * 64];  // K tile [kv][d], chunk-swizzled, double-buffered
  __shared__ u16 Vs[2][64 * 64];  // V^T tile [d][kv], chunk-swizzled, double-buffered
  __shared__ u16 P[128 * 72];     // P [qrow][kv], stride 72, per-warp private rows
  const int tid = threadIdx.x, lane = tid & 63, w = tid >> 6;
  const int b = blockIdx.z, h = blockIdx.y, qb = blockIdx.x;
  const u16* qp = qk + (size_t)b * 2048 * 1536 + h * 64;
  const u16* kp = qp + 768;
  const u16* vtp = vt + (size_t)(h * 64) * 8192 + b * 2048;
  const int lr = lane & 15, g = lane >> 4, lk = g * 8;
  const int qrow = qb * 128 + w * 32;

  // Q fragments for 2 q-groups, pre-scaled by 0.125 * log2(e) (exp2 domain); used as B operand.
  bf16x8 qf[2][2];
#pragma unroll
  for (int gq = 0; gq < 2; ++gq) {
#pragma unroll
    for (int t = 0; t < 2; ++t) {
      s16x8 qr = *(const s16x8*)&qp[(size_t)(qrow + gq * 16 + lr) * 1536 + t * 32 + lk];
      bf16x8 f;
#pragma unroll
      for (int j = 0; j < 8; ++j) {
        unsigned u = (unsigned)(u16)qr[j] << 16;
        f[j] = (__bf16)(__uint_as_float(u) * 0.18033688f);
      }
      qf[gq][t] = f;
    }
  }

  // constant ones A-fragment for rowsum-via-MFMA
  bf16x8 onesf;
#pragma unroll
  for (int j = 0; j < 8; ++j) onesf[j] = (__bf16)1.0f;

  f32x4 o[2][4] = {};  // [gq][di]: O^T tiles, row=d, col=q
  f32x4 o4[2] = {};    // row-sum accumulators (every row = column sum)
  float rowm[2] = {-1e30f, -1e30f};

#define STAGE(bi, kv)                                                          \
  do {                                                                         \
    _Pragma("unroll") for (int i_ = 0; i_ < 2; ++i_) {                         \
      const int ch = i_ * 256 + tid;                                           \
      const int r_ = ch >> 3, c_ = ch & 7, cs_ = c_ ^ (r_ & 7);                \
      load_lds16(kp + (size_t)((kv) + r_) * 1536 + cs_ * 8, &Ks[bi][ch * 8]);  \
      load_lds16(vtp + (size_t)r_ * 8192 + (kv) + cs_ * 8, &Vs[bi][ch * 8]);   \
    }                                                                          \
  } while (0)

  STAGE(0, 0);
  __syncthreads();
  int cur = 0;

  for (int kv0 = 0; kv0 < 2048; kv0 += 64) {
    if (kv0 + 64 < 2048) STAGE(cur ^ 1, kv0 + 64);  // prefetch next tile; lands by the barrier

    // swapped QK^T: S^T[kv][q]; lane holds 16 kv-scores for one q
    f32x4 s[2][4] = {};
#pragma unroll
    for (int t = 0; t < 2; ++t) {
#pragma unroll
      for (int ni = 0; ni < 4; ++ni) {
        const int r = ni * 16 + lr;
        bf16x8 kf = *(const bf16x8*)&Ks[cur][r * 64 + ((4 * t + g) ^ (lr & 7)) * 8];
        s[0][ni] = mfma16(kf, qf[0][t], s[0][ni]);
        s[1][ni] = mfma16(kf, qf[1][t], s[1][ni]);
      }
    }

    // defer-max: lane-local max over 16 values per gq; shfl-free common path
    float lm[2];
#pragma unroll
    for (int gq = 0; gq < 2; ++gq) {
      float m0 = fmaxf(fmaxf(s[gq][0][0], s[gq][0][1]), fmaxf(s[gq][0][2], s[gq][0][3]));
      float m1 = fmaxf(fmaxf(s[gq][1][0], s[gq][1][1]), fmaxf(s[gq][1][2], s[gq][1][3]));
      float m2 = fmaxf(fmaxf(s[gq][2][0], s[gq][2][1]), fmaxf(s[gq][2][2], s[gq][2][3]));
      float m3 = fmaxf(fmaxf(s[gq][3][0], s[gq][3][1]), fmaxf(s[gq][3][2], s[gq][3][3]));
      lm[gq] = fmaxf(fmaxf(m0, m1), fmaxf(m2, m3));
    }
    const int ok = (lm[0] <= rowm[0] + 8.f) & (lm[1] <= rowm[1] + 8.f);
    if (!__all(ok)) {
#pragma unroll
      for (int gq = 0; gq < 2; ++gq) {
        float v = lm[gq];
        v = fmaxf(v, __shfl_xor(v, 16));
        v = fmaxf(v, __shfl_xor(v, 32));
        const float mn = fmaxf(rowm[gq], v);
        const float alpha = fexp2(rowm[gq] - mn);
        rowm[gq] = mn;
#pragma unroll
        for (int di = 0; di < 4; ++di) o[gq][di] *= alpha;
        o4[gq] *= alpha;
      }
    }

    // P = exp2(S - rowm), packed bf16 pairs, b32 writes to per-warp LDS rows
    unsigned* Pw = (unsigned*)P;
#pragma unroll
    for (int gq = 0; gq < 2; ++gq) {
      const int qrl = w * 32 + gq * 16 + lr;
#pragma unroll
      for (int ni = 0; ni < 4; ++ni) {
#pragma unroll
        for (int r = 0; r < 2; ++r) {
          const float p0 = fexp2(s[gq][ni][2 * r] - rowm[gq]);
          const float p1 = fexp2(s[gq][ni][2 * r + 1] - rowm[gq]);
          Pw[(qrl * 72 + ni * 16 + 4 * g + 2 * r) >> 1] = cvtpk(p0, p1);
        }
      }
    }

    // PV: O^T += V^T * P (A = V^T tile, B = P rows); ones-A accumulates row sums
#pragma unroll
    for (int t = 0; t < 2; ++t) {
      bf16x8 pb0 = *(const bf16x8*)&P[(w * 32 + lr) * 72 + t * 32 + g * 8];
      bf16x8 pb1 = *(const bf16x8*)&P[(w * 32 + 16 + lr) * 72 + t * 32 + g * 8];
#pragma unroll
      for (int di = 0; di < 4; ++di) {
        bf16x8 va = *(const bf16x8*)&Vs[cur][(di * 16 + lr) * 64 + ((4 * t + g) ^ (lr & 7)) * 8];
        o[0][di] = mfma16(va, pb0, o[0][di]);
        o[1][di] = mfma16(va, pb1, o[1][di]);
      }
      o4[0] = mfma16(onesf, pb0, o4[0]);
      o4[1] = mfma16(onesf, pb1, o4[1]);
    }

    __syncthreads();  // drains prefetch (vmcnt) + all waves done reading buf[cur]
    cur ^= 1;
  }
#undef STAGE

  // epilogue: normalize and store; lane's 4 rr values are d-contiguous -> packed 8B stores
#pragma unroll
  for (int gq = 0; gq < 2; ++gq) {
    const float inv = 1.0f / o4[gq][0];
    const size_t n = (size_t)b * 2048 + qrow + gq * 16 + lr;
#pragma unroll
    for (int di = 0; di < 4; ++di) {
      uint2 uv;
      uv.x = cvtpk(o[gq][di][0] * inv, o[gq][di][1] * inv);
      uv.y = cvtpk(o[gq][di][2] * inv, o[gq][di][3] * inv);
      *(uint2*)&out[n * 768 + h * 64 + di * 16 + 4 * g] = uv;
    }
  }
}

extern "C" void kernel_launch(void* const* d_in, const int* in_sizes, int n_in,
                              void* d_out, int out_size, void* d_ws, size_t ws_size,
                              hipStream_t stream) {
  const float* x     = (const float*)d_in[0];
  const float* y     = (const float*)d_in[1];
  const float* g1    = (const float*)d_in[4];
  const float* be1   = (const float*)d_in[5];
  const float* g2    = (const float*)d_in[6];
  const float* be2   = (const float*)d_in[7];
  const float* g3    = (const float*)d_in[8];
  const float* be3   = (const float*)d_in[9];
  const float* gy    = (const float*)d_in[10];
  const float* bey   = (const float*)d_in[11];
  const float* Wqkv  = (const float*)d_in[12];
  const float* Wo_sa = (const float*)d_in[13];
  const float* bo_sa = (const float*)d_in[14];
  const float* Wq    = (const float*)d_in[15];
  const float* Wk    = (const float*)d_in[16];
  const float* Wv    = (const float*)d_in[17];
  const float* Wo_ca = (const float*)d_in[18];
  const float* bo_ca = (const float*)d_in[19];
  const float* W1    = (const float*)d_in[20];
  const float* b1    = (const float*)d_in[21];
  const float* W2    = (const float*)d_in[22];
  const float* b2    = (const float*)d_in[23];

  // workspace (u16 units), total 94.4 MB
  u16* WqkvT = (u16*)d_ws;                        // [2304][768]
  u16* WoSaT = WqkvT + (size_t)2304 * 768;        // [768][768]
  u16* WqT   = WoSaT + (size_t)768 * 768;
  u16* WkT   = WqT   + (size_t)768 * 768;
  u16* WvT   = WkT   + (size_t)768 * 768;
  u16* WoCaT = WvT   + (size_t)768 * 768;
  u16* W1T   = WoCaT + (size_t)768 * 768;         // [3072][768]
  u16* W2T   = W1T   + (size_t)3072 * 768;        // [768][3072]
  u16* R1    = W2T   + (size_t)768 * 3072;        // [8192][3072]: qk [8192][1536] / mlp hidden
  u16* VT    = R1    + (size_t)8192 * 1536;       // [768][8192] V^T (upper half of R1 region)
  u16* R2    = R1    + (size_t)8192 * 3072;       // [8192][768]
  u16* R3    = R2    + (size_t)8192 * 768;        // [8192][768]
  float* xo  = (float*)d_out;                     // fp32 residual spine x1/x2/out

  WT8 wa;
  {
    const float* s8[8] = {Wqkv, Wo_sa, Wq, Wk, Wv, Wo_ca, W1, W2};
    u16* d8[8] = {WqkvT, WoSaT, WqT, WkT, WvT, WoCaT, W1T, W2T};
    const int K8[8] = {768, 768, 768, 768, 768, 768, 768, 3072};
    const int N8[8] = {2304, 768, 768, 768, 768, 768, 3072, 768};
    for (int i = 0; i < 8; ++i) {
      wa.src[i] = s8[i]; wa.dst[i] = d8[i];
      wa.K[i] = K8[i]; wa.N[i] = N8[i];
      wa.cnt[i] = (N8[i] / 32) * (K8[i] / 32);
    }
  }
  wtrans_all<<<9216, dim3(32, 8), 0, stream>>>(wa);

  // --- self attention ---
  ln_bf16<<<8192, 256, 0, stream>>>(x, g1, be1, R2);
  gemm_bt<0, 128><<<dim3(12, 64), 256, 0, stream>>>(R2, WqkvT, nullptr, nullptr, R1, 8192, 1536, 768, 1536);
  gemm_bt<0, 64><<<dim3(64, 12), 256, 0, stream>>>(WqkvT + (size_t)1536 * 768, R2, nullptr, nullptr, VT, 768, 8192, 768, 8192);
  flash_attn<<<dim3(16, 12, 4), 256, 0, stream>>>(R1, VT, R2);
  gemm_bt<1, 64><<<dim3(6, 128), 256, 0, stream>>>(R2, WoSaT, bo_sa, x, xo, 8192, 768, 768, 768);

  // --- cross attention ---
  ln_bf16<<<8192, 256, 0, stream>>>(y, gy, bey, R3);
  ln_bf16<<<8192, 256, 0, stream>>>(xo, g2, be2, R2);
  gemm_bt<0, 64><<<dim3(6, 128), 256, 0, stream>>>(R2, WqT, nullptr, nullptr, R1, 8192, 768, 768, 1536);
  gemm_bt<0, 64><<<dim3(6, 128), 256, 0, stream>>>(R3, WkT, nullptr, nullptr, R1 + 768, 8192, 768, 768, 1536);
  gemm_bt<0, 64><<<dim3(64, 12), 256, 0, stream>>>(WvT, R3, nullptr, nullptr, VT, 768, 8192, 768, 8192);
  flash_attn<<<dim3(16, 12, 4), 256, 0, stream>>>(R1, VT, R3);
  gemm_bt<1, 64><<<dim3(6, 128), 256, 0, stream>>>(R3, WoCaT, bo_ca, xo, xo, 8192, 768, 768, 768);

  // --- MLP ---
  ln_bf16<<<8192, 256, 0, stream>>>(xo, g3, be3, R2);
  gemm_bt<2, 128><<<dim3(24, 64), 256, 0, stream>>>(R2, W1T, b1, nullptr, R1, 8192, 3072, 768, 3072);
  gemm_bt<1, 64><<<dim3(6, 128), 256, 0, stream>>>(R1, W2T, b2, xo, xo, 8192, 768, 3072, 768);
}

// Round 15
// 461.045 us; speedup vs baseline: 1.2339x; 1.0148x over previous
//
#include <hip/hip_runtime.h>
#include <math.h>

typedef unsigned short u16;
typedef __attribute__((ext_vector_type(4))) float f32x4;
typedef __attribute__((ext_vector_type(8))) __bf16 bf16x8;
typedef __attribute__((ext_vector_type(8))) short s16x8;

#define AS1 __attribute__((address_space(1)))
#define AS3 __attribute__((address_space(3)))

__device__ __forceinline__ u16 cvt(float f) {
  __bf16 h = (__bf16)f;
  return *(u16*)&h;
}

__device__ __forceinline__ unsigned cvtpk(float lo, float hi) {
  unsigned r;
  asm("v_cvt_pk_bf16_f32 %0, %1, %2" : "=v"(r) : "v"(lo), "v"(hi));
  return r;
}

__device__ __forceinline__ float fexp2(float x) {
  float r;
  asm volatile("v_exp_f32 %0, %1" : "=v"(r) : "v"(x));
  return r;
}

__device__ __forceinline__ void load_lds16(const void* g, void* l) {
  __builtin_amdgcn_global_load_lds((AS1 void*)g, (AS3 void*)l, 16, 0, 0);
}

__device__ __forceinline__ f32x4 mfma16(bf16x8 a, bf16x8 b, f32x4 c) {
  return __builtin_amdgcn_mfma_f32_16x16x32_bf16(a, b, c, 0, 0, 0);
}

// ---------------- merged weight transpose fp32 -> bf16, W[K][N] -> WT[N][K] ----------------
struct WT8 {
  const float* src[8];
  u16* dst[8];
  int K[8];
  int N[8];
  int cnt[8];  // (N/32)*(K/32)
};

__global__ void wtrans_all(WT8 a) {
  __shared__ float t[32][33];
  int rem = blockIdx.x, i = 0;
  while (rem >= a.cnt[i]) { rem -= a.cnt[i]; ++i; }
  const int nb = a.N[i] >> 5;
  const int n0 = (rem % nb) * 32, k0 = (rem / nb) * 32;
  const float* W = a.src[i];
  u16* WT = a.dst[i];
  const int K = a.K[i], N = a.N[i];
  for (int r = threadIdx.y; r < 32; r += 8)
    t[r][threadIdx.x] = W[(size_t)(k0 + r) * N + n0 + threadIdx.x];
  __syncthreads();
  for (int r = threadIdx.y; r < 32; r += 8)
    WT[(size_t)(n0 + r) * K + k0 + threadIdx.x] = cvt(t[threadIdx.x][r]);
}

// ---------------- LayerNorm fp32 -> bf16 (row = 768) ----------------
__global__ __launch_bounds__(256)
void ln_bf16(const float* __restrict__ in, const float* __restrict__ g,
             const float* __restrict__ be, u16* __restrict__ out) {
  const int row = blockIdx.x, tid = threadIdx.x;
  const float* x = in + (size_t)row * 768;
  float v0 = x[tid], v1 = x[tid + 256], v2 = x[tid + 512];
  float s = v0 + v1 + v2;
  for (int m = 1; m < 64; m <<= 1) s += __shfl_xor(s, m);
  __shared__ float red[8];
  const int w = tid >> 6, lane = tid & 63;
  if (lane == 0) red[w] = s;
  __syncthreads();
  s = red[0] + red[1] + red[2] + red[3];
  const float mean = s * (1.f / 768.f);
  const float d0 = v0 - mean, d1 = v1 - mean, d2 = v2 - mean;
  float q = d0 * d0 + d1 * d1 + d2 * d2;
  for (int m = 1; m < 64; m <<= 1) q += __shfl_xor(q, m);
  if (lane == 0) red[4 + w] = q;
  __syncthreads();
  q = red[4] + red[5] + red[6] + red[7];
  const float rstd = rsqrtf(q * (1.f / 768.f) + 1e-5f);
  u16* o = out + (size_t)row * 768;
  o[tid]       = cvt(d0 * rstd * g[tid]       + be[tid]);
  o[tid + 256] = cvt(d1 * rstd * g[tid + 256] + be[tid + 256]);
  o[tid + 512] = cvt(d2 * rstd * g[tid + 512] + be[tid + 512]);
}

// ---------------- GEMM: C[M][N] = A[M][K] * BT[N][K]^T ----------------
// Unified BK=64, XOR chunk-swizzled LDS, XCD-chunked block swizzle, 3 blocks/CU.
// BM=128: 4 waves 64x64. BM=64: 4 waves 64x32.
// EPI 0: bf16 out (ldc stride). EPI 1: fp32 out = acc + bias + resid. EPI 2: bf16 gelu(acc+bias).
template <int EPI, int BM>
__global__ __launch_bounds__(256, 3)
void gemm_bt(const u16* __restrict__ A, const u16* __restrict__ BT,
             const float* __restrict__ bias, const float* resid,
             void* outp, int M, int N, int K, int ldc) {
  constexpr int NI = (BM == 128) ? 4 : 2;
  __shared__ u16 As[BM * 64];
  __shared__ u16 Bs[128 * 64];
  const int tid = threadIdx.x;
  const int lane = tid & 63, w = tid >> 6;
  const int lr = lane & 15, g = lane >> 4;

  int bx = blockIdx.x, by = blockIdx.y;
  {
    // bijective XCD-chunked swizzle: XCD k owns a contiguous logical chunk
    const int nwg = gridDim.x * gridDim.y;
    if ((nwg & 7) == 0) {
      const int d = by * gridDim.x + bx;
      const int l = (d & 7) * (nwg >> 3) + (d >> 3);
      bx = l % gridDim.x;
      by = l / gridDim.x;
    }
  }
  const int row0 = by * BM, col0 = bx * 128;
  const int wm = (BM == 128) ? (w >> 1) * 64 : 0;
  const int wn = (BM == 128) ? (w & 1) * 64 : w * 32;

  f32x4 acc[4][NI] = {};

  for (int k0 = 0; k0 < K; k0 += 64) {
#pragma unroll
    for (int i = 0; i < BM / 32; ++i) {
      const int ch = i * 256 + tid;
      const int r = ch >> 3, c = ch & 7, cs = c ^ (r & 7);
      load_lds16(A + (size_t)(row0 + r) * K + k0 + cs * 8, &As[ch * 8]);
    }
#pragma unroll
    for (int i = 0; i < 4; ++i) {
      const int ch = i * 256 + tid;
      const int r = ch >> 3, c = ch & 7, cs = c ^ (r & 7);
      load_lds16(BT + (size_t)(col0 + r) * K + k0 + cs * 8, &Bs[ch * 8]);
    }
    __syncthreads();
#pragma unroll
    for (int kk = 0; kk < 2; ++kk) {
      bf16x8 af[4], bf[NI];
#pragma unroll
      for (int mi = 0; mi < 4; ++mi) {
        const int r = wm + mi * 16 + lr;
        af[mi] = *(const bf16x8*)&As[r * 64 + (((kk * 4 + g) ^ (lr & 7)) * 8)];
      }
#pragma unroll
      for (int ni = 0; ni < NI; ++ni) {
        const int r = wn + ni * 16 + lr;
        bf[ni] = *(const bf16x8*)&Bs[r * 64 + (((kk * 4 + g) ^ (lr & 7)) * 8)];
      }
#pragma unroll
      for (int mi = 0; mi < 4; ++mi)
#pragma unroll
        for (int ni = 0; ni < NI; ++ni)
          acc[mi][ni] = mfma16(af[mi], bf[ni], acc[mi][ni]);
    }
    __syncthreads();
  }

  const int rbase = g * 4;
#pragma unroll
  for (int mi = 0; mi < 4; ++mi) {
#pragma unroll
    for (int ni = 0; ni < NI; ++ni) {
#pragma unroll
      for (int rr = 0; rr < 4; ++rr) {
        const int r = row0 + wm + mi * 16 + rbase + rr;
        const int c = col0 + wn + ni * 16 + lr;
        float v = acc[mi][ni][rr];
        if (EPI == 0) {
          ((u16*)outp)[(size_t)r * ldc + c] = cvt(v);
        } else if (EPI == 1) {
          ((float*)outp)[(size_t)r * ldc + c] = v + bias[c] + resid[(size_t)r * ldc + c];
        } else {
          v += bias[c];
          v = 0.5f * v * (1.f + erff(v * 0.70710678118654752f));
          ((u16*)outp)[(size_t)r * ldc + c] = cvt(v);
        }
      }
    }
  }
}

// ---------------- Flash attention (swapped QK^T: q in C-columns) ----------------
// qk: [8192][1536] bf16 (q at col h*64, k at col 768+h*64), vt: [768][8192] bf16 (V^T, row h*64+d)
// out: [8192][768] bf16
__global__ __launch_bounds__(256, 3)
void flash_attn(const u16* __restrict__ qk, const u16* __restrict__ vt, u16* __restrict__ out) {
  __shared__ u16 Ks[2][64 * 64];  // K tile [kv][d], chunk-swizzled, double-buffered
  __shared__ u16 Vs[2][64 * 64];  // V^T tile [d][kv], chunk-swizzled, double-buffered
  __shared__ u16 P[128 * 72];     // P [qrow][kv], stride 72, per-warp private rows
  const int tid = threadIdx.x, lane = tid & 63, w = tid >> 6;
  const int b = blockIdx.z, h = blockIdx.y, qb = blockIdx.x;
  const u16* qp = qk + (size_t)b * 2048 * 1536 + h * 64;
  const u16* kp = qp + 768;
  const u16* vtp = vt + (size_t)(h * 64) * 8192 + b * 2048;
  const int lr = lane & 15, g = lane >> 4, lk = g * 8;
  const int qrow = qb * 128 + w * 32;

  // Q fragments for 2 q-groups, pre-scaled by 0.125 * log2(e) (exp2 domain); used as B operand.
  bf16x8 qf[2][2];
#pragma unroll
  for (int gq = 0; gq < 2; ++gq) {
#pragma unroll
    for (int t = 0; t < 2; ++t) {
      s16x8 qr = *(const s16x8*)&qp[(size_t)(qrow + gq * 16 + lr) * 1536 + t * 32 + lk];
      bf16x8 f;
#pragma unroll
      for (int j = 0; j < 8; ++j) {
        unsigned u = (unsigned)(u16)qr[j] << 16;
        f[j] = (__bf16)(__uint_as_float(u) * 0.18033688f);
      }
      qf[gq][t] = f;
    }
  }

  // constant ones A-fragment for rowsum-via-MFMA
  bf16x8 onesf;
#pragma unroll
  for (int j = 0; j < 8; ++j) onesf[j] = (__bf16)1.0f;

  f32x4 o[2][4] = {};  // [gq][di]: O^T tiles, row=d, col=q
  f32x4 o4[2] = {};    // row-sum accumulators (every row = column sum)
  float rowm[2] = {-1e30f, -1e30f};

#define STAGE(bi, kv)                                                          \
  do {                                                                         \
    _Pragma("unroll") for (int i_ = 0; i_ < 2; ++i_) {                         \
      const int ch = i_ * 256 + tid;                                           \
      const int r_ = ch >> 3, c_ = ch & 7, cs_ = c_ ^ (r_ & 7);                \
      load_lds16(kp + (size_t)((kv) + r_) * 1536 + cs_ * 8, &Ks[bi][ch * 8]);  \
      load_lds16(vtp + (size_t)r_ * 8192 + (kv) + cs_ * 8, &Vs[bi][ch * 8]);   \
    }                                                                          \
  } while (0)

  STAGE(0, 0);
  __syncthreads();
  int cur = 0;

  for (int kv0 = 0; kv0 < 2048; kv0 += 64) {
    if (kv0 + 64 < 2048) STAGE(cur ^ 1, kv0 + 64);  // prefetch next tile; lands by the barrier

    // swapped QK^T: S^T[kv][q]; lane holds 16 kv-scores for one q
    f32x4 s[2][4] = {};
#pragma unroll
    for (int t = 0; t < 2; ++t) {
#pragma unroll
      for (int ni = 0; ni < 4; ++ni) {
        const int r = ni * 16 + lr;
        bf16x8 kf = *(const bf16x8*)&Ks[cur][r * 64 + ((4 * t + g) ^ (lr & 7)) * 8];
        s[0][ni] = mfma16(kf, qf[0][t], s[0][ni]);
        s[1][ni] = mfma16(kf, qf[1][t], s[1][ni]);
      }
    }

    // defer-max: lane-local max over 16 values per gq (max3-friendly); shfl-free common path
    float lm[2];
#pragma unroll
    for (int gq = 0; gq < 2; ++gq) {
      float a = fmaxf(fmaxf(s[gq][0][0], s[gq][0][1]), s[gq][0][2]);
      float b2 = fmaxf(fmaxf(s[gq][0][3], s[gq][1][0]), s[gq][1][1]);
      float c = fmaxf(fmaxf(s[gq][1][2], s[gq][1][3]), s[gq][2][0]);
      float d = fmaxf(fmaxf(s[gq][2][1], s[gq][2][2]), s[gq][2][3]);
      float e = fmaxf(fmaxf(s[gq][3][0], s[gq][3][1]), s[gq][3][2]);
      lm[gq] = fmaxf(fmaxf(fmaxf(a, b2), fmaxf(c, d)), fmaxf(e, s[gq][3][3]));
    }
    const int ok = (lm[0] <= rowm[0] + 8.f) & (lm[1] <= rowm[1] + 8.f);
    if (!__all(ok)) {
#pragma unroll
      for (int gq = 0; gq < 2; ++gq) {
        float v = lm[gq];
        v = fmaxf(v, __shfl_xor(v, 16));
        v = fmaxf(v, __shfl_xor(v, 32));
        const float mn = fmaxf(rowm[gq], v);
        const float alpha = fexp2(rowm[gq] - mn);
        rowm[gq] = mn;
#pragma unroll
        for (int di = 0; di < 4; ++di) o[gq][di] *= alpha;
        o4[gq] *= alpha;
      }
    }

    // P = exp2(S - rowm), packed bf16 pairs, b64 writes (8B aligned) to per-warp LDS rows
#pragma unroll
    for (int gq = 0; gq < 2; ++gq) {
      const int qrl = w * 32 + gq * 16 + lr;
#pragma unroll
      for (int ni = 0; ni < 4; ++ni) {
        uint2 pv;
        pv.x = cvtpk(fexp2(s[gq][ni][0] - rowm[gq]), fexp2(s[gq][ni][1] - rowm[gq]));
        pv.y = cvtpk(fexp2(s[gq][ni][2] - rowm[gq]), fexp2(s[gq][ni][3] - rowm[gq]));
        *(uint2*)&P[qrl * 72 + ni * 16 + 4 * g] = pv;
      }
    }

    // PV: O^T += V^T * P (A = V^T tile, B = P rows); ones-A accumulates row sums
    __builtin_amdgcn_s_setprio(1);
#pragma unroll
    for (int t = 0; t < 2; ++t) {
      bf16x8 pb0 = *(const bf16x8*)&P[(w * 32 + lr) * 72 + t * 32 + g * 8];
      bf16x8 pb1 = *(const bf16x8*)&P[(w * 32 + 16 + lr) * 72 + t * 32 + g * 8];
#pragma unroll
      for (int di = 0; di < 4; ++di) {
        bf16x8 va = *(const bf16x8*)&Vs[cur][(di * 16 + lr) * 64 + ((4 * t + g) ^ (lr & 7)) * 8];
        o[0][di] = mfma16(va, pb0, o[0][di]);
        o[1][di] = mfma16(va, pb1, o[1][di]);
      }
      o4[0] = mfma16(onesf, pb0, o4[0]);
      o4[1] = mfma16(onesf, pb1, o4[1]);
    }
    __builtin_amdgcn_s_setprio(0);

    __syncthreads();  // drains prefetch (vmcnt) + all waves done reading buf[cur]
    cur ^= 1;
  }
#undef STAGE

  // epilogue: normalize and store; lane's 4 rr values are d-contiguous -> packed 8B stores
#pragma unroll
  for (int gq = 0; gq < 2; ++gq) {
    const float inv = 1.0f / o4[gq][0];
    const size_t n = (size_t)b * 2048 + qrow + gq * 16 + lr;
#pragma unroll
    for (int di = 0; di < 4; ++di) {
      uint2 uv;
      uv.x = cvtpk(o[gq][di][0] * inv, o[gq][di][1] * inv);
      uv.y = cvtpk(o[gq][di][2] * inv, o[gq][di][3] * inv);
      *(uint2*)&out[n * 768 + h * 64 + di * 16 + 4 * g] = uv;
    }
  }
}

extern "C" void kernel_launch(void* const* d_in, const int* in_sizes, int n_in,
                              void* d_out, int out_size, void* d_ws, size_t ws_size,
                              hipStream_t stream) {
  const float* x     = (const float*)d_in[0];
  const float* y     = (const float*)d_in[1];
  const float* g1    = (const float*)d_in[4];
  const float* be1   = (const float*)d_in[5];
  const float* g2    = (const float*)d_in[6];
  const float* be2   = (const float*)d_in[7];
  const float* g3    = (const float*)d_in[8];
  const float* be3   = (const float*)d_in[9];
  const float* gy    = (const float*)d_in[10];
  const float* bey   = (const float*)d_in[11];
  const float* Wqkv  = (const float*)d_in[12];
  const float* Wo_sa = (const float*)d_in[13];
  const float* bo_sa = (const float*)d_in[14];
  const float* Wq    = (const float*)d_in[15];
  const float* Wk    = (const float*)d_in[16];
  const float* Wv    = (const float*)d_in[17];
  const float* Wo_ca = (const float*)d_in[18];
  const float* bo_ca = (const float*)d_in[19];
  const float* W1    = (const float*)d_in[20];
  const float* b1    = (const float*)d_in[21];
  const float* W2    = (const float*)d_in[22];
  const float* b2    = (const float*)d_in[23];

  // workspace (u16 units), total 94.4 MB
  u16* WqkvT = (u16*)d_ws;                        // [2304][768]
  u16* WoSaT = WqkvT + (size_t)2304 * 768;        // [768][768]
  u16* WqT   = WoSaT + (size_t)768 * 768;
  u16* WkT   = WqT   + (size_t)768 * 768;
  u16* WvT   = WkT   + (size_t)768 * 768;
  u16* WoCaT = WvT   + (size_t)768 * 768;
  u16* W1T   = WoCaT + (size_t)768 * 768;         // [3072][768]
  u16* W2T   = W1T   + (size_t)3072 * 768;        // [768][3072]
  u16* R1    = W2T   + (size_t)768 * 3072;        // [8192][3072]: qk [8192][1536] / mlp hidden
  u16* VT    = R1    + (size_t)8192 * 1536;       // [768][8192] V^T (upper half of R1 region)
  u16* R2    = R1    + (size_t)8192 * 3072;       // [8192][768]
  u16* R3    = R2    + (size_t)8192 * 768;        // [8192][768]
  float* xo  = (float*)d_out;                     // fp32 residual spine x1/x2/out

  WT8 wa;
  {
    const float* s8[8] = {Wqkv, Wo_sa, Wq, Wk, Wv, Wo_ca, W1, W2};
    u16* d8[8] = {WqkvT, WoSaT, WqT, WkT, WvT, WoCaT, W1T, W2T};
    const int K8[8] = {768, 768, 768, 768, 768, 768, 768, 3072};
    const int N8[8] = {2304, 768, 768, 768, 768, 768, 3072, 768};
    for (int i = 0; i < 8; ++i) {
      wa.src[i] = s8[i]; wa.dst[i] = d8[i];
      wa.K[i] = K8[i]; wa.N[i] = N8[i];
      wa.cnt[i] = (N8[i] / 32) * (K8[i] / 32);
    }
  }
  wtrans_all<<<9216, dim3(32, 8), 0, stream>>>(wa);

  // --- self attention ---
  ln_bf16<<<8192, 256, 0, stream>>>(x, g1, be1, R2);
  gemm_bt<0, 128><<<dim3(12, 64), 256, 0, stream>>>(R2, WqkvT, nullptr, nullptr, R1, 8192, 1536, 768, 1536);
  gemm_bt<0, 64><<<dim3(64, 12), 256, 0, stream>>>(WqkvT + (size_t)1536 * 768, R2, nullptr, nullptr, VT, 768, 8192, 768, 8192);
  flash_attn<<<dim3(16, 12, 4), 256, 0, stream>>>(R1, VT, R2);
  gemm_bt<1, 64><<<dim3(6, 128), 256, 0, stream>>>(R2, WoSaT, bo_sa, x, xo, 8192, 768, 768, 768);

  // --- cross attention ---
  ln_bf16<<<8192, 256, 0, stream>>>(y, gy, bey, R3);
  ln_bf16<<<8192, 256, 0, stream>>>(xo, g2, be2, R2);
  gemm_bt<0, 64><<<dim3(6, 128), 256, 0, stream>>>(R2, WqT, nullptr, nullptr, R1, 8192, 768, 768, 1536);
  gemm_bt<0, 64><<<dim3(6, 128), 256, 0, stream>>>(R3, WkT, nullptr, nullptr, R1 + 768, 8192, 768, 768, 1536);
  gemm_bt<0, 64><<<dim3(64, 12), 256, 0, stream>>>(WvT, R3, nullptr, nullptr, VT, 768, 8192, 768, 8192);
  flash_attn<<<dim3(16, 12, 4), 256, 0, stream>>>(R1, VT, R3);
  gemm_bt<1, 64><<<dim3(6, 128), 256, 0, stream>>>(R3, WoCaT, bo_ca, xo, xo, 8192, 768, 768, 768);

  // --- MLP ---
  ln_bf16<<<8192, 256, 0, stream>>>(xo, g3, be3, R2);
  gemm_bt<2, 128><<<dim3(24, 64), 256, 0, stream>>>(R2, W1T, b1, nullptr, R1, 8192, 3072, 768, 3072);
  gemm_bt<1, 64><<<dim3(6, 128), 256, 0, stream>>>(R1, W2T, b2, xo, xo, 8192, 768, 3072, 768);
}

// Round 16
// 457.571 us; speedup vs baseline: 1.2433x; 1.0076x over previous
//
#include <hip/hip_runtime.h>
#include <math.h>

typedef unsigned short u16;
typedef __attribute__((ext_vector_type(4))) float f32x4;
typedef __attribute__((ext_vector_type(8))) __bf16 bf16x8;
typedef __attribute__((ext_vector_type(8))) short s16x8;

#define AS1 __attribute__((address_space(1)))
#define AS3 __attribute__((address_space(3)))

__device__ __forceinline__ u16 cvt(float f) {
  __bf16 h = (__bf16)f;
  return *(u16*)&h;
}

__device__ __forceinline__ unsigned cvtpk(float lo, float hi) {
  unsigned r;
  asm("v_cvt_pk_bf16_f32 %0, %1, %2" : "=v"(r) : "v"(lo), "v"(hi));
  return r;
}

__device__ __forceinline__ float fexp2(float x) {
  float r;
  asm volatile("v_exp_f32 %0, %1" : "=v"(r) : "v"(x));
  return r;
}

__device__ __forceinline__ void load_lds16(const void* g, void* l) {
  __builtin_amdgcn_global_load_lds((AS1 void*)g, (AS3 void*)l, 16, 0, 0);
}

__device__ __forceinline__ f32x4 mfma16(bf16x8 a, bf16x8 b, f32x4 c) {
  return __builtin_amdgcn_mfma_f32_16x16x32_bf16(a, b, c, 0, 0, 0);
}

// ---------------- merged weight transpose fp32 -> bf16, W[K][N] -> WT[N][K] ----------------
struct WT8 {
  const float* src[8];
  u16* dst[8];
  int K[8];
  int N[8];
  int cnt[8];  // (N/32)*(K/32)
};

__global__ void wtrans_all(WT8 a) {
  __shared__ float t[32][33];
  int rem = blockIdx.x, i = 0;
  while (rem >= a.cnt[i]) { rem -= a.cnt[i]; ++i; }
  const int nb = a.N[i] >> 5;
  const int n0 = (rem % nb) * 32, k0 = (rem / nb) * 32;
  const float* W = a.src[i];
  u16* WT = a.dst[i];
  const int K = a.K[i], N = a.N[i];
  for (int r = threadIdx.y; r < 32; r += 8)
    t[r][threadIdx.x] = W[(size_t)(k0 + r) * N + n0 + threadIdx.x];
  __syncthreads();
  for (int r = threadIdx.y; r < 32; r += 8)
    WT[(size_t)(n0 + r) * K + k0 + threadIdx.x] = cvt(t[threadIdx.x][r]);
}

// ---------------- LayerNorm fp32 -> bf16 (row = 768) ----------------
__global__ __launch_bounds__(256)
void ln_bf16(const float* __restrict__ in, const float* __restrict__ g,
             const float* __restrict__ be, u16* __restrict__ out) {
  const int row = blockIdx.x, tid = threadIdx.x;
  const float* x = in + (size_t)row * 768;
  float v0 = x[tid], v1 = x[tid + 256], v2 = x[tid + 512];
  float s = v0 + v1 + v2;
  for (int m = 1; m < 64; m <<= 1) s += __shfl_xor(s, m);
  __shared__ float red[8];
  const int w = tid >> 6, lane = tid & 63;
  if (lane == 0) red[w] = s;
  __syncthreads();
  s = red[0] + red[1] + red[2] + red[3];
  const float mean = s * (1.f / 768.f);
  const float d0 = v0 - mean, d1 = v1 - mean, d2 = v2 - mean;
  float q = d0 * d0 + d1 * d1 + d2 * d2;
  for (int m = 1; m < 64; m <<= 1) q += __shfl_xor(q, m);
  if (lane == 0) red[4 + w] = q;
  __syncthreads();
  q = red[4] + red[5] + red[6] + red[7];
  const float rstd = rsqrtf(q * (1.f / 768.f) + 1e-5f);
  u16* o = out + (size_t)row * 768;
  o[tid]       = cvt(d0 * rstd * g[tid]       + be[tid]);
  o[tid + 256] = cvt(d1 * rstd * g[tid + 256] + be[tid + 256]);
  o[tid + 512] = cvt(d2 * rstd * g[tid + 512] + be[tid + 512]);
}

// ---------------- GEMM: C[M][N] = A[M][K] * BT[N][K]^T ----------------
// Unified BK=64, XOR chunk-swizzled LDS, XCD-chunked block swizzle, 3 blocks/CU.
// BM=128: 4 waves 64x64. BM=64: 4 waves 64x32.
// EPI 0: bf16 out (ldc stride). EPI 1: fp32 out = acc + bias + resid. EPI 2: bf16 gelu(acc+bias).
template <int EPI, int BM>
__global__ __launch_bounds__(256, 3)
void gemm_bt(const u16* __restrict__ A, const u16* __restrict__ BT,
             const float* __restrict__ bias, const float* resid,
             void* outp, int M, int N, int K, int ldc) {
  constexpr int NI = (BM == 128) ? 4 : 2;
  __shared__ u16 As[BM * 64];
  __shared__ u16 Bs[128 * 64];
  const int tid = threadIdx.x;
  const int lane = tid & 63, w = tid >> 6;
  const int lr = lane & 15, g = lane >> 4;

  int bx = blockIdx.x, by = blockIdx.y;
  {
    // bijective XCD-chunked swizzle: XCD k owns a contiguous logical chunk
    const int nwg = gridDim.x * gridDim.y;
    if ((nwg & 7) == 0) {
      const int d = by * gridDim.x + bx;
      const int l = (d & 7) * (nwg >> 3) + (d >> 3);
      bx = l % gridDim.x;
      by = l / gridDim.x;
    }
  }
  const int row0 = by * BM, col0 = bx * 128;
  const int wm = (BM == 128) ? (w >> 1) * 64 : 0;
  const int wn = (BM == 128) ? (w & 1) * 64 : w * 32;

  f32x4 acc[4][NI] = {};

  for (int k0 = 0; k0 < K; k0 += 64) {
#pragma unroll
    for (int i = 0; i < BM / 32; ++i) {
      const int ch = i * 256 + tid;
      const int r = ch >> 3, c = ch & 7, cs = c ^ (r & 7);
      load_lds16(A + (size_t)(row0 + r) * K + k0 + cs * 8, &As[ch * 8]);
    }
#pragma unroll
    for (int i = 0; i < 4; ++i) {
      const int ch = i * 256 + tid;
      const int r = ch >> 3, c = ch & 7, cs = c ^ (r & 7);
      load_lds16(BT + (size_t)(col0 + r) * K + k0 + cs * 8, &Bs[ch * 8]);
    }
    __syncthreads();
#pragma unroll
    for (int kk = 0; kk < 2; ++kk) {
      bf16x8 af[4], bf[NI];
#pragma unroll
      for (int mi = 0; mi < 4; ++mi) {
        const int r = wm + mi * 16 + lr;
        af[mi] = *(const bf16x8*)&As[r * 64 + (((kk * 4 + g) ^ (lr & 7)) * 8)];
      }
#pragma unroll
      for (int ni = 0; ni < NI; ++ni) {
        const int r = wn + ni * 16 + lr;
        bf[ni] = *(const bf16x8*)&Bs[r * 64 + (((kk * 4 + g) ^ (lr & 7)) * 8)];
      }
#pragma unroll
      for (int mi = 0; mi < 4; ++mi)
#pragma unroll
        for (int ni = 0; ni < NI; ++ni)
          acc[mi][ni] = mfma16(af[mi], bf[ni], acc[mi][ni]);
    }
    __syncthreads();
  }

  const int rbase = g * 4;
#pragma unroll
  for (int mi = 0; mi < 4; ++mi) {
#pragma unroll
    for (int ni = 0; ni < NI; ++ni) {
#pragma unroll
      for (int rr = 0; rr < 4; ++rr) {
        const int r = row0 + wm + mi * 16 + rbase + rr;
        const int c = col0 + wn + ni * 16 + lr;
        float v = acc[mi][ni][rr];
        if (EPI == 0) {
          ((u16*)outp)[(size_t)r * ldc + c] = cvt(v);
        } else if (EPI == 1) {
          ((float*)outp)[(size_t)r * ldc + c] = v + bias[c] + resid[(size_t)r * ldc + c];
        } else {
          v += bias[c];
          v = 0.5f * v * (1.f + erff(v * 0.70710678118654752f));
          ((u16*)outp)[(size_t)r * ldc + c] = cvt(v);
        }
      }
    }
  }
}

// ---------------- Flash attention (swapped QK^T: q in C-columns) ----------------
// qk: [8192][1536] bf16 (q at col h*64, k at col 768+h*64), vt: [768][8192] bf16 (V^T, row h*64+d)
// out: [8192][768] bf16
__global__ __launch_bounds__(256, 3)
void flash_attn(const u16* __restrict__ qk, const u16* __restrict__ vt, u16* __restrict__ out) {
  __shared__ u16 Ks[2][64 * 64];  // K tile [kv][d], chunk-swizzled, double-buffered
  __shared__ u16 Vs[2][64 * 64];  // V^T tile [d][kv], chunk-swizzled, double-buffered
  __shared__ u16 P[128 * 64];     // P [qrow][kv], stride 64, XOR chunk-swizzled like K/V
  const int tid = threadIdx.x, lane = tid & 63, w = tid >> 6;
  const int b = blockIdx.z, h = blockIdx.y, qb = blockIdx.x;
  const u16* qp = qk + (size_t)b * 2048 * 1536 + h * 64;
  const u16* kp = qp + 768;
  const u16* vtp = vt + (size_t)(h * 64) * 8192 + b * 2048;
  const int lr = lane & 15, g = lane >> 4, lk = g * 8;
  const int qrow = qb * 128 + w * 32;

  // Q fragments for 2 q-groups, pre-scaled by 0.125 * log2(e) (exp2 domain); used as B operand.
  bf16x8 qf[2][2];
#pragma unroll
  for (int gq = 0; gq < 2; ++gq) {
#pragma unroll
    for (int t = 0; t < 2; ++t) {
      s16x8 qr = *(const s16x8*)&qp[(size_t)(qrow + gq * 16 + lr) * 1536 + t * 32 + lk];
      bf16x8 f;
#pragma unroll
      for (int j = 0; j < 8; ++j) {
        unsigned u = (unsigned)(u16)qr[j] << 16;
        f[j] = (__bf16)(__uint_as_float(u) * 0.18033688f);
      }
      qf[gq][t] = f;
    }
  }

  // constant ones A-fragment for rowsum-via-MFMA
  bf16x8 onesf;
#pragma unroll
  for (int j = 0; j < 8; ++j) onesf[j] = (__bf16)1.0f;

  f32x4 o[2][4] = {};  // [gq][di]: O^T tiles, row=d, col=q
  f32x4 o4[2] = {};    // row-sum accumulators (every row = column sum)
  float rowm[2] = {-1e30f, -1e30f};

#define STAGE(bi, kv)                                                          \
  do {                                                                         \
    _Pragma("unroll") for (int i_ = 0; i_ < 2; ++i_) {                         \
      const int ch = i_ * 256 + tid;                                           \
      const int r_ = ch >> 3, c_ = ch & 7, cs_ = c_ ^ (r_ & 7);                \
      load_lds16(kp + (size_t)((kv) + r_) * 1536 + cs_ * 8, &Ks[bi][ch * 8]);  \
      load_lds16(vtp + (size_t)r_ * 8192 + (kv) + cs_ * 8, &Vs[bi][ch * 8]);   \
    }                                                                          \
  } while (0)

  STAGE(0, 0);
  __syncthreads();
  int cur = 0;

  for (int kv0 = 0; kv0 < 2048; kv0 += 64) {
    if (kv0 + 64 < 2048) STAGE(cur ^ 1, kv0 + 64);  // prefetch next tile; lands by the barrier

    // swapped QK^T: S^T[kv][q]; lane holds 16 kv-scores for one q
    f32x4 s[2][4] = {};
#pragma unroll
    for (int t = 0; t < 2; ++t) {
#pragma unroll
      for (int ni = 0; ni < 4; ++ni) {
        const int r = ni * 16 + lr;
        bf16x8 kf = *(const bf16x8*)&Ks[cur][r * 64 + ((4 * t + g) ^ (lr & 7)) * 8];
        s[0][ni] = mfma16(kf, qf[0][t], s[0][ni]);
        s[1][ni] = mfma16(kf, qf[1][t], s[1][ni]);
      }
    }

    // defer-max: lane-local max over 16 values per gq (max3-friendly); shfl-free common path
    float lm[2];
#pragma unroll
    for (int gq = 0; gq < 2; ++gq) {
      float a = fmaxf(fmaxf(s[gq][0][0], s[gq][0][1]), s[gq][0][2]);
      float b2 = fmaxf(fmaxf(s[gq][0][3], s[gq][1][0]), s[gq][1][1]);
      float c = fmaxf(fmaxf(s[gq][1][2], s[gq][1][3]), s[gq][2][0]);
      float d = fmaxf(fmaxf(s[gq][2][1], s[gq][2][2]), s[gq][2][3]);
      float e = fmaxf(fmaxf(s[gq][3][0], s[gq][3][1]), s[gq][3][2]);
      lm[gq] = fmaxf(fmaxf(fmaxf(a, b2), fmaxf(c, d)), fmaxf(e, s[gq][3][3]));
    }
    const int ok = (lm[0] <= rowm[0] + 8.f) & (lm[1] <= rowm[1] + 8.f);
    if (!__all(ok)) {
#pragma unroll
      for (int gq = 0; gq < 2; ++gq) {
        float v = lm[gq];
        v = fmaxf(v, __shfl_xor(v, 16));
        v = fmaxf(v, __shfl_xor(v, 32));
        const float mn = fmaxf(rowm[gq], v);
        const float alpha = fexp2(rowm[gq] - mn);
        rowm[gq] = mn;
#pragma unroll
        for (int di = 0; di < 4; ++di) o[gq][di] *= alpha;
        o4[gq] *= alpha;
      }
    }

    // P = exp2(S - rowm), packed bf16 pairs, b64 writes to XOR-swizzled stride-64 rows.
    // Lane's 4 values (kv = ni*16+4g+0..3) = chunk 2ni+(g>>1), sub-offset 4*(g&1);
    // per fixed lr the 4 g-lanes tile chunks {2ni, 2ni+1} bijectively -> bank floor.
#pragma unroll
    for (int gq = 0; gq < 2; ++gq) {
      const int qrl = w * 32 + gq * 16 + lr;
#pragma unroll
      for (int ni = 0; ni < 4; ++ni) {
        uint2 pv;
        pv.x = cvtpk(fexp2(s[gq][ni][0] - rowm[gq]), fexp2(s[gq][ni][1] - rowm[gq]));
        pv.y = cvtpk(fexp2(s[gq][ni][2] - rowm[gq]), fexp2(s[gq][ni][3] - rowm[gq]));
        *(uint2*)&P[qrl * 64 + (((2 * ni + (g >> 1)) ^ (lr & 7)) * 8) + 4 * (g & 1)] = pv;
      }
    }

    // PV: O^T += V^T * P (A = V^T tile, B = P rows); ones-A accumulates row sums
    __builtin_amdgcn_s_setprio(1);
#pragma unroll
    for (int t = 0; t < 2; ++t) {
      bf16x8 pb0 = *(const bf16x8*)&P[(w * 32 + lr) * 64 + ((4 * t + g) ^ (lr & 7)) * 8];
      bf16x8 pb1 = *(const bf16x8*)&P[(w * 32 + 16 + lr) * 64 + ((4 * t + g) ^ (lr & 7)) * 8];
#pragma unroll
      for (int di = 0; di < 4; ++di) {
        bf16x8 va = *(const bf16x8*)&Vs[cur][(di * 16 + lr) * 64 + ((4 * t + g) ^ (lr & 7)) * 8];
        o[0][di] = mfma16(va, pb0, o[0][di]);
        o[1][di] = mfma16(va, pb1, o[1][di]);
      }
      o4[0] = mfma16(onesf, pb0, o4[0]);
      o4[1] = mfma16(onesf, pb1, o4[1]);
    }
    __builtin_amdgcn_s_setprio(0);

    __syncthreads();  // drains prefetch (vmcnt) + all waves done reading buf[cur]
    cur ^= 1;
  }
#undef STAGE

  // epilogue: normalize and store; lane's 4 rr values are d-contiguous -> packed 8B stores
#pragma unroll
  for (int gq = 0; gq < 2; ++gq) {
    const float inv = 1.0f / o4[gq][0];
    const size_t n = (size_t)b * 2048 + qrow + gq * 16 + lr;
#pragma unroll
    for (int di = 0; di < 4; ++di) {
      uint2 uv;
      uv.x = cvtpk(o[gq][di][0] * inv, o[gq][di][1] * inv);
      uv.y = cvtpk(o[gq][di][2] * inv, o[gq][di][3] * inv);
      *(uint2*)&out[n * 768 + h * 64 + di * 16 + 4 * g] = uv;
    }
  }
}

extern "C" void kernel_launch(void* const* d_in, const int* in_sizes, int n_in,
                              void* d_out, int out_size, void* d_ws, size_t ws_size,
                              hipStream_t stream) {
  const float* x     = (const float*)d_in[0];
  const float* y     = (const float*)d_in[1];
  const float* g1    = (const float*)d_in[4];
  const float* be1   = (const float*)d_in[5];
  const float* g2    = (const float*)d_in[6];
  const float* be2   = (const float*)d_in[7];
  const float* g3    = (const float*)d_in[8];
  const float* be3   = (const float*)d_in[9];
  const float* gy    = (const float*)d_in[10];
  const float* bey   = (const float*)d_in[11];
  const float* Wqkv  = (const float*)d_in[12];
  const float* Wo_sa = (const float*)d_in[13];
  const float* bo_sa = (const float*)d_in[14];
  const float* Wq    = (const float*)d_in[15];
  const float* Wk    = (const float*)d_in[16];
  const float* Wv    = (const float*)d_in[17];
  const float* Wo_ca = (const float*)d_in[18];
  const float* bo_ca = (const float*)d_in[19];
  const float* W1    = (const float*)d_in[20];
  const float* b1    = (const float*)d_in[21];
  const float* W2    = (const float*)d_in[22];
  const float* b2    = (const float*)d_in[23];

  // workspace (u16 units), total 94.4 MB
  u16* WqkvT = (u16*)d_ws;                        // [2304][768]
  u16* WoSaT = WqkvT + (size_t)2304 * 768;        // [768][768]
  u16* WqT   = WoSaT + (size_t)768 * 768;
  u16* WkT   = WqT   + (size_t)768 * 768;
  u16* WvT   = WkT   + (size_t)768 * 768;
  u16* WoCaT = WvT   + (size_t)768 * 768;
  u16* W1T   = WoCaT + (size_t)768 * 768;         // [3072][768]
  u16* W2T   = W1T   + (size_t)3072 * 768;        // [768][3072]
  u16* R1    = W2T   + (size_t)768 * 3072;        // [8192][3072]: qk [8192][1536] / mlp hidden
  u16* VT    = R1    + (size_t)8192 * 1536;       // [768][8192] V^T (upper half of R1 region)
  u16* R2    = R1    + (size_t)8192 * 3072;       // [8192][768]
  u16* R3    = R2    + (size_t)8192 * 768;        // [8192][768]
  float* xo  = (float*)d_out;                     // fp32 residual spine x1/x2/out

  WT8 wa;
  {
    const float* s8[8] = {Wqkv, Wo_sa, Wq, Wk, Wv, Wo_ca, W1, W2};
    u16* d8[8] = {WqkvT, WoSaT, WqT, WkT, WvT, WoCaT, W1T, W2T};
    const int K8[8] = {768, 768, 768, 768, 768, 768, 768, 3072};
    const int N8[8] = {2304, 768, 768, 768, 768, 768, 3072, 768};
    for (int i = 0; i < 8; ++i) {
      wa.src[i] = s8[i]; wa.dst[i] = d8[i];
      wa.K[i] = K8[i]; wa.N[i] = N8[i];
      wa.cnt[i] = (N8[i] / 32) * (K8[i] / 32);
    }
  }
  wtrans_all<<<9216, dim3(32, 8), 0, stream>>>(wa);

  // --- self attention ---
  ln_bf16<<<8192, 256, 0, stream>>>(x, g1, be1, R2);
  gemm_bt<0, 128><<<dim3(12, 64), 256, 0, stream>>>(R2, WqkvT, nullptr, nullptr, R1, 8192, 1536, 768, 1536);
  gemm_bt<0, 64><<<dim3(64, 12), 256, 0, stream>>>(WqkvT + (size_t)1536 * 768, R2, nullptr, nullptr, VT, 768, 8192, 768, 8192);
  flash_attn<<<dim3(16, 12, 4), 256, 0, stream>>>(R1, VT, R2);
  gemm_bt<1, 64><<<dim3(6, 128), 256, 0, stream>>>(R2, WoSaT, bo_sa, x, xo, 8192, 768, 768, 768);

  // --- cross attention ---
  ln_bf16<<<8192, 256, 0, stream>>>(y, gy, bey, R3);
  ln_bf16<<<8192, 256, 0, stream>>>(xo, g2, be2, R2);
  gemm_bt<0, 64><<<dim3(6, 128), 256, 0, stream>>>(R2, WqT, nullptr, nullptr, R1, 8192, 768, 768, 1536);
  gemm_bt<0, 64><<<dim3(6, 128), 256, 0, stream>>>(R3, WkT, nullptr, nullptr, R1 + 768, 8192, 768, 768, 1536);
  gemm_bt<0, 64><<<dim3(64, 12), 256, 0, stream>>>(WvT, R3, nullptr, nullptr, VT, 768, 8192, 768, 8192);
  flash_attn<<<dim3(16, 12, 4), 256, 0, stream>>>(R1, VT, R3);
  gemm_bt<1, 64><<<dim3(6, 128), 256, 0, stream>>>(R3, WoCaT, bo_ca, xo, xo, 8192, 768, 768, 768);

  // --- MLP ---
  ln_bf16<<<8192, 256, 0, stream>>>(xo, g3, be3, R2);
  gemm_bt<2, 128><<<dim3(24, 64), 256, 0, stream>>>(R2, W1T, b1, nullptr, R1, 8192, 3072, 768, 3072);
  gemm_bt<1, 64><<<dim3(6, 128), 256, 0, stream>>>(R1, W2T, b2, xo, xo, 8192, 768, 3072, 768);
}